// Round 4
// baseline (8135.013 us; speedup 1.0000x reference)
//
#include <hip/hip_runtime.h>

#define NATOM 10000
#define EG    120000
#define TT    600000

#define INV_SQRT2f 0.7071067811865476f

typedef unsigned short bf16t;

__device__ __forceinline__ float ssilu(float x) {
    return x * (1.0f / (1.0f + __expf(-x))) * (1.0f / 0.6f);
}
__device__ __forceinline__ float bf2f(unsigned short u) {
    return __uint_as_float(((unsigned)u) << 16);
}
__device__ __forceinline__ unsigned short f2bf(float f) {
    unsigned b = __float_as_uint(f);
    unsigned r = (b + 0x7FFF + ((b >> 16) & 1)) >> 16;  // RNE
    return (unsigned short)r;
}

template <typename T> struct VT;
template <> struct VT<float> {
    static __device__ __forceinline__ float4 load4(const float* p) { return *(const float4*)p; }
    static __device__ __forceinline__ void store4(float* p, float4 v) { *(float4*)p = v; }
    static __device__ __forceinline__ float load(const float* p) { return *p; }
    static __device__ __forceinline__ void store(float* p, float v) { *p = v; }
};
template <> struct VT<bf16t> {
    static __device__ __forceinline__ float4 load4(const bf16t* p) {
        ushort4 u = *(const ushort4*)p;
        return make_float4(bf2f(u.x), bf2f(u.y), bf2f(u.z), bf2f(u.w));
    }
    static __device__ __forceinline__ void store4(bf16t* p, float4 v) {
        ushort4 u; u.x = f2bf(v.x); u.y = f2bf(v.y); u.z = f2bf(v.z); u.w = f2bf(v.w);
        *(ushort4*)p = u;
    }
    static __device__ __forceinline__ float load(const bf16t* p) { return bf2f(*p); }
    static __device__ __forceinline__ void store(bf16t* p, float v) { *p = f2bf(v); }
};

// ---------------------------------------------------------------------------
__global__ __launch_bounds__(256) void k_fill(float* __restrict__ o, int n, float v) {
    int i = blockIdx.x * 256 + threadIdx.x;
    if (i < n) o[i] = v;
}

// ---------------------------------------------------------------------------
// combined weight: Wc[16,256] = Wa[16,16] @ Wb[16,256]
// ---------------------------------------------------------------------------
__global__ __launch_bounds__(256) void k_wcomb(
    const float* __restrict__ Wa, const float* __restrict__ Wb, float* __restrict__ Wc)
{
    __shared__ float sA[256];
    int j = threadIdx.x;
    sA[j] = Wa[j];
    __syncthreads();
#pragma unroll 4
    for (int r = 0; r < 16; r++) {
        float acc = 0.f;
#pragma unroll
        for (int k = 0; k < 16; k++) acc = fmaf(sA[r * 16 + k], Wb[k * 256 + j], acc);
        Wc[r * 256 + j] = acc;
    }
}

// ---------------------------------------------------------------------------
// rbf basis + rbf_W1 (cbf down-projection)
// ---------------------------------------------------------------------------
template <typename T>
__global__ __launch_bounds__(256) void k_rbf(
    const float* __restrict__ D, const float* __restrict__ Wc,
    T* __restrict__ rbf, float* __restrict__ rbfW1)
{
    __shared__ float sW[1792];
    for (int i = threadIdx.x; i < 1792; i += 256) sW[i] = Wc[i];
    __syncthreads();
    int e = blockIdx.x * 256 + threadIdx.x;
    if (e >= EG) return;
    float d = D[e] * (1.0f / 6.0f);
    float d2 = d * d, d4 = d2 * d2, d5 = d4 * d, d6 = d5 * d, d7 = d6 * d;
    float env = 1.0f - 21.0f * d5 + 35.0f * d6 - 15.0f * d7;
    if (d >= 1.0f) env = 0.0f;
    float r[16];
#pragma unroll
    for (int i = 0; i < 16; i++) {
        float t = d - (float)i * (1.0f / 15.0f);
        r[i] = env * __expf(-112.5f * t * t);
    }
#pragma unroll
    for (int j = 0; j < 16; j++) VT<T>::store(rbf + (size_t)e * 16 + j, r[j]);
    for (int s = 0; s < 7; s++) {
#pragma unroll 4
        for (int i = 0; i < 16; i++) {
            float a = 0.f;
#pragma unroll
            for (int k = 0; k < 16; k++)
                a = fmaf(r[k], sW[(s * 16 + k) * 16 + i], a);
            rbfW1[(size_t)e * 112 + s * 16 + i] = a;
        }
    }
}

// ---------------------------------------------------------------------------
// spherical basis + cbf_t
// ---------------------------------------------------------------------------
template <typename T>
__global__ __launch_bounds__(256) void k_cbf(
    const float* __restrict__ cosphi, const int* __restrict__ id3_ca,
    const float* __restrict__ rbfW1, T* __restrict__ cbf)
{
    int t = blockIdx.x * 256 + threadIdx.x;
    if (t >= TT) return;
    float c = cosphi[t];
    const float norm[7] = {0.28209479177387814f, 0.4886025119029199f, 0.6307831305050401f,
                           0.7463526651802308f, 0.8462843753216345f, 0.935414346693485f,
                           1.0171072362820548f};
    float y[7];
    float pm2 = 1.0f, pm1 = c;
    y[0] = norm[0];
    y[1] = norm[1] * c;
    for (int l = 2; l < 7; l++) {
        float p = ((2.0f * l - 1.0f) * c * pm1 - (l - 1.0f) * pm2) / (float)l;
        y[l] = norm[l] * p;
        pm2 = pm1; pm1 = p;
    }
    int e = id3_ca[t];
    const float* __restrict__ w = rbfW1 + (size_t)e * 112;
    float out[16];
#pragma unroll
    for (int i = 0; i < 16; i++) out[i] = 0.f;
#pragma unroll
    for (int s = 0; s < 7; s++) {
        float ys = y[s];
#pragma unroll
        for (int i = 0; i < 16; i++) out[i] = fmaf(ys, w[s * 16 + i], out[i]);
    }
#pragma unroll
    for (int i = 0; i < 16; i += 4)
        VT<T>::store4(cbf + (size_t)t * 16 + i, make_float4(out[i], out[i + 1], out[i + 2], out[i + 3]));
}

// ---------------------------------------------------------------------------
__global__ __launch_bounds__(256) void k_hgather(
    const float* __restrict__ emb, const int* __restrict__ Z, float* __restrict__ h)
{
    int i = blockIdx.x * 256 + threadIdx.x;
    if (i < NATOM * 128) {
        int n = i >> 7, j = i & 127;
        h[i] = emb[(size_t)Z[n] * 128 + j];
    }
}

// ---------------------------------------------------------------------------
// tiled f32-compute GEMM: C[M,N] = epi(A[M,K] @ B[K,N]); storage types TA/TC
// AMODE 0: plain A;  AMODE 1: A row r = concat(hA[gS[r]],hA[gT[r]],X[r,0:w2])
// EPI 1: ssilu; 2: (skip+ssilu)*inv2; 3: C[swp[r]]=(C[swp[r]]+ssilu)*inv2
// ---------------------------------------------------------------------------
template <typename TA, typename TC, int AMODE, int EPI>
__global__ __launch_bounds__(256) void gemm64(
    const TA* __restrict__ A, const float* __restrict__ B,
    TC* __restrict__ C, const TC* __restrict__ skip,
    int M, int N, int K,
    const float* __restrict__ hA, const int* __restrict__ gS,
    const int* __restrict__ gT, const TA* __restrict__ X, int w2,
    const int* __restrict__ swp)
{
    __shared__ __align__(16) float As[16][64];
    __shared__ __align__(16) float Bs[16][64];
    const int tid = threadIdx.x;
    const int tx = tid & 15, ty = tid >> 4;
    const int rowBase = blockIdx.y * 64;
    const int colBase = blockIdx.x * 64;
    const int lr = tid >> 2;
    const int lk = (tid & 3) * 4;
    const int bk = tid >> 4;
    const int bc = (tid & 15) * 4;
    int arow = rowBase + lr;
    int arowC = arow < M ? arow : (M - 1);
    int ia = 0, ib = 0;
    if (AMODE == 1) { ia = gS[arowC]; ib = gT[arowC]; }

    float acc[4][4];
#pragma unroll
    for (int i = 0; i < 4; i++)
#pragma unroll
        for (int j = 0; j < 4; j++) acc[i][j] = 0.f;

    for (int k0 = 0; k0 < K; k0 += 16) {
        float4 a4, b4;
        if (AMODE == 0) {
            a4 = VT<TA>::load4(A + (size_t)arowC * K + k0 + lk);
        } else {
            int k = k0 + lk;
            if (k < 128)       a4 = *(const float4*)(hA + (size_t)ia * 128 + k);
            else if (k < 256)  a4 = *(const float4*)(hA + (size_t)ib * 128 + (k - 128));
            else               a4 = VT<TA>::load4(X + (size_t)arowC * w2 + (k - 256));
        }
        b4 = *(const float4*)(B + (size_t)(k0 + bk) * N + colBase + bc);
        __syncthreads();
        As[lk + 0][lr] = a4.x;
        As[lk + 1][lr] = a4.y;
        As[lk + 2][lr] = a4.z;
        As[lk + 3][lr] = a4.w;
        *(float4*)(&Bs[bk][bc]) = b4;
        __syncthreads();
#pragma unroll
        for (int kk = 0; kk < 16; kk++) {
            float4 av = *(const float4*)(&As[kk][ty * 4]);
            float4 bv = *(const float4*)(&Bs[kk][tx * 4]);
            float a[4] = {av.x, av.y, av.z, av.w};
            float b[4] = {bv.x, bv.y, bv.z, bv.w};
#pragma unroll
            for (int i = 0; i < 4; i++)
#pragma unroll
                for (int j = 0; j < 4; j++)
                    acc[i][j] = fmaf(a[i], b[j], acc[i][j]);
        }
    }
    const int col0 = colBase + tx * 4;
#pragma unroll
    for (int ri = 0; ri < 4; ri++) {
        int row = rowBase + ty * 4 + ri;
        if (row >= M) break;
        if (EPI == 3) {
            int trow = swp[row];
            TC* cp = C + (size_t)trow * N + col0;
#pragma unroll
            for (int ci = 0; ci < 4; ci++) {
                float v = ssilu(acc[ri][ci]);
                VT<TC>::store(cp + ci, (VT<TC>::load(cp + ci) + v) * INV_SQRT2f);
            }
        } else {
            TC* cp = C + (size_t)row * N + col0;
#pragma unroll
            for (int ci = 0; ci < 4; ci++) {
                float v = acc[ri][ci];
                if (EPI == 1) v = ssilu(v);
                if (EPI == 2) v = (VT<TC>::load(skip + (size_t)row * N + col0 + ci) + ssilu(v)) * INV_SQRT2f;
                VT<TC>::store(cp + ci, v);
            }
        }
    }
}

// ---------------------------------------------------------------------------
// bilinear triplet kernel: seg[id3_ca[t]] += (outer(xt[id3_ba[t]],cbf[t]) @ Wf)
// ---------------------------------------------------------------------------
template <typename T>
__global__ __launch_bounds__(256) void k_bilinear(
    const T* __restrict__ xtrip, const T* __restrict__ cbf,
    const float* __restrict__ Wb,
    const int* __restrict__ id3_ba, const int* __restrict__ id3_ca,
    float* __restrict__ seg)
{
    __shared__ __align__(16) float xt[64][64];
    __shared__ __align__(16) float Bs[64][64];
    const int tid = threadIdx.x;
    const int t0 = blockIdx.x * 64;
    {
        int r = tid >> 2;
        int q = (tid & 3) * 16;
        int ba = id3_ba[t0 + r];
        const T* src = xtrip + (size_t)ba * 64 + q;
        float4* dst = (float4*)(&xt[r][q]);
        dst[0] = VT<T>::load4(src);
        dst[1] = VT<T>::load4(src + 4);
        dst[2] = VT<T>::load4(src + 8);
        dst[3] = VT<T>::load4(src + 12);
    }
    const int tx = tid & 15, ty = tid >> 4;
    float cb[4][16];
#pragma unroll
    for (int rr = 0; rr < 4; rr++) {
        const T* c4 = cbf + (size_t)(t0 + ty * 4 + rr) * 16;
#pragma unroll
        for (int q = 0; q < 4; q++) {
            float4 v = VT<T>::load4(c4 + q * 4);
            cb[rr][q * 4 + 0] = v.x; cb[rr][q * 4 + 1] = v.y;
            cb[rr][q * 4 + 2] = v.z; cb[rr][q * 4 + 3] = v.w;
        }
    }
    float acc[4][4];
#pragma unroll
    for (int i = 0; i < 4; i++)
#pragma unroll
        for (int j = 0; j < 4; j++) acc[i][j] = 0.f;

    for (int kc = 0; kc < 16; kc++) {
        __syncthreads();
        {
            int kr = tid >> 2;
            int q = (tid & 3) * 16;
            const float4* src = (const float4*)(Wb + (size_t)(kc * 64 + kr) * 64 + q);
            float4* dst = (float4*)(&Bs[kr][q]);
            dst[0] = src[0]; dst[1] = src[1]; dst[2] = src[2]; dst[3] = src[3];
        }
        __syncthreads();
#pragma unroll
        for (int cl = 0; cl < 4; cl++) {
            float ax[4];
#pragma unroll
            for (int rr = 0; rr < 4; rr++) ax[rr] = xt[ty * 4 + rr][kc * 4 + cl];
#pragma unroll
            for (int i = 0; i < 16; i++) {
                int kk = cl * 16 + i;
                float4 bv = *(const float4*)(&Bs[kk][tx * 4]);
                float b[4] = {bv.x, bv.y, bv.z, bv.w};
                float a[4];
#pragma unroll
                for (int rr = 0; rr < 4; rr++) a[rr] = ax[rr] * cb[rr][i];
#pragma unroll
                for (int rr = 0; rr < 4; rr++)
#pragma unroll
                    for (int cc = 0; cc < 4; cc++)
                        acc[rr][cc] = fmaf(a[rr], b[cc], acc[rr][cc]);
            }
        }
    }
#pragma unroll
    for (int rr = 0; rr < 4; rr++) {
        int trow = t0 + ty * 4 + rr;
        int ca = id3_ca[trow];
        float* sp = seg + (size_t)ca * 64 + tx * 4;
#pragma unroll
        for (int cc = 0; cc < 4; cc++) atomicAdd(&sp[cc], acc[rr][cc]);
    }
}

// ---------------------------------------------------------------------------
// per-edge multiply by (rbf[e,16] @ Wc[16,256]); SCATTER: atomicAdd f32 to idxT
// ---------------------------------------------------------------------------
template <int SCATTER, typename T>
__global__ __launch_bounds__(256) void k_mulproj(
    const T* __restrict__ in, const T* __restrict__ rvec,
    const float* __restrict__ Wp, const int* __restrict__ idxT,
    T* __restrict__ out, float* __restrict__ outf)
{
    int e = blockIdx.x;
    int j = threadIdx.x;
    __shared__ float r16[16];
    if (j < 16) r16[j] = VT<T>::load(rvec + (size_t)e * 16 + j);
    __syncthreads();
    float p = 0.f;
#pragma unroll
    for (int k = 0; k < 16; k++) p = fmaf(r16[k], Wp[k * 256 + j], p);
    float v = VT<T>::load(in + (size_t)e * 256 + j) * p;
    if (SCATTER) atomicAdd(&outf[(size_t)idxT[e] * 256 + j], v);
    else VT<T>::store(out + (size_t)e * 256 + j, v);
}

// ---------------------------------------------------------------------------
// LN(m row) * (rbf[e,16] @ Wc[16,256]) scattered into segN (f32) by idx_t
// ---------------------------------------------------------------------------
template <typename T>
__global__ __launch_bounds__(256) void k_ln_proj_scatter(
    const T* __restrict__ m, const float* __restrict__ lnw,
    const float* __restrict__ lnb, const T* __restrict__ rvec,
    const float* __restrict__ Wp, const int* __restrict__ idxT,
    float* __restrict__ segN)
{
    int e = blockIdx.x;
    int j = threadIdx.x;
    __shared__ float red[8];
    __shared__ float r16[16];
    if (j < 16) r16[j] = VT<T>::load(rvec + (size_t)e * 16 + j);
    float v = VT<T>::load(m + (size_t)e * 256 + j);
    float s = v, s2 = v * v;
#pragma unroll
    for (int off = 32; off > 0; off >>= 1) {
        s += __shfl_xor(s, off);
        s2 += __shfl_xor(s2, off);
    }
    int wid = j >> 6, lane = j & 63;
    if (lane == 0) { red[wid] = s; red[4 + wid] = s2; }
    __syncthreads();
    float tot = red[0] + red[1] + red[2] + red[3];
    float tot2 = red[4] + red[5] + red[6] + red[7];
    float mu = tot * (1.f / 256.f);
    float var = tot2 * (1.f / 256.f) - mu * mu;
    float ln = (v - mu) * rsqrtf(var + 1e-5f) * lnw[j] + lnb[j];
    float p = 0.f;
#pragma unroll
    for (int k = 0; k < 16; k++) p = fmaf(r16[k], Wp[k * 256 + j], p);
    atomicAdd(&segN[(size_t)idxT[e] * 256 + j], ln * p);
}

// ---------------------------------------------------------------------------
__global__ __launch_bounds__(128) void k_ln_acc(
    const float* __restrict__ x, const float* __restrict__ w,
    const float* __restrict__ b, float* __restrict__ out)
{
    int n = blockIdx.x;
    int j = threadIdx.x;
    __shared__ float red[4];
    float v = x[(size_t)n * 128 + j];
    float s = v, s2 = v * v;
#pragma unroll
    for (int off = 32; off > 0; off >>= 1) {
        s += __shfl_xor(s, off);
        s2 += __shfl_xor(s2, off);
    }
    int wid = j >> 6, lane = j & 63;
    if (lane == 0) { red[wid] = s; red[2 + wid] = s2; }
    __syncthreads();
    float tot = red[0] + red[1];
    float tot2 = red[2] + red[3];
    float mu = tot * (1.f / 128.f);
    float var = tot2 * (1.f / 128.f) - mu * mu;
    out[(size_t)n * 128 + j] += (v - mu) * rsqrtf(var + 1e-5f) * w[j] + b[j];
}

// ---------------------------------------------------------------------------
template <typename T>
__global__ __launch_bounds__(256) void k_addscale(
    const T* __restrict__ a, const T* __restrict__ b, T* __restrict__ y, int n4)
{
    int i = blockIdx.x * 256 + threadIdx.x;
    if (i < n4) {
        float4 av = VT<T>::load4(a + (size_t)i * 4);
        float4 bv = VT<T>::load4(b + (size_t)i * 4);
        VT<T>::store4(y + (size_t)i * 4,
                      make_float4((av.x + bv.x) * INV_SQRT2f, (av.y + bv.y) * INV_SQRT2f,
                                  (av.z + bv.z) * INV_SQRT2f, (av.w + bv.w) * INV_SQRT2f));
    }
}

// ---------------------------------------------------------------------------
template <typename T>
static bool try_run(void* const* d_in, void* d_out, void* d_ws, size_t ws_size, hipStream_t stream)
{
    const float* D            = (const float*)d_in[0];
    const float* cosphi       = (const float*)d_in[1];
    const float* atom_emb     = (const float*)d_in[2];
    const float* W_rbf3       = (const float*)d_in[3];
    const float* W_rbf_h      = (const float*)d_in[4];
    const float* W_rbf_out    = (const float*)d_in[5];
    const float* W_cbf_down   = (const float*)d_in[6];
    const float* W_edge_emb   = (const float*)d_in[7];
    const float* ib_dense_ca  = (const float*)d_in[8];
    const float* ib_trip_dense_ba = (const float*)d_in[9];
    const float* ib_trip_mlp_rbf  = (const float*)d_in[10];
    const float* ib_trip_down     = (const float*)d_in[11];
    const float* ib_trip_bilinear = (const float*)d_in[12];
    const float* ib_trip_up_ca    = (const float*)d_in[13];
    const float* ib_trip_up_ac    = (const float*)d_in[14];
    const float* ib_res_before    = (const float*)d_in[15];
    const float* ib_res_after     = (const float*)d_in[16];
    const float* ib_atom_dense_rbf = (const float*)d_in[17];
    const float* ib_atom_dense1    = (const float*)d_in[18];
    const float* ib_atom_res       = (const float*)d_in[19];
    const float* ib_concat_dense   = (const float*)d_in[20];
    const float* ib_res_m          = (const float*)d_in[21];
    const float* ob_dense_rbf      = (const float*)d_in[22];
    const float* ob_dense1         = (const float*)d_in[23];
    const float* ob_res            = (const float*)d_in[24];
    const float* ln_m_w            = (const float*)d_in[25];
    const float* ln_m_b            = (const float*)d_in[26];
    const float* ln_E_w            = (const float*)d_in[27];
    const float* ln_E_b            = (const float*)d_in[28];
    const int* Z       = (const int*)d_in[29];
    const int* idx_s   = (const int*)d_in[30];
    const int* idx_t   = (const int*)d_in[31];
    const int* id3_ba  = (const int*)d_in[32];
    const int* id3_ca  = (const int*)d_in[33];
    const int* id_swap = (const int*)d_in[34];

    const size_t sT = sizeof(T);
    char* base = (char*)d_ws;
    size_t off = 0;
    auto alloc = [&](size_t bytes) -> char* {
        off = (off + 255) & ~(size_t)255;
        char* p = base + off;
        off += bytes;
        return p;
    };
    T* m      = (T*)alloc((size_t)EG * 256 * sT);
    T* B1     = (T*)alloc((size_t)EG * 256 * sT);
    T* B2     = (T*)alloc((size_t)EG * 256 * sT);
    float* rbfW1 = (float*)B1;                    // alias: dead before B1 first written
    T* rbf    = (T*)alloc((size_t)EG * 16 * sT);  // persistent basis
    T* cbf    = (T*)alloc((size_t)TT * 16 * sT);
    float* h  = (float*)alloc((size_t)NATOM * 128 * 4);
    T* xtrip  = (T*)alloc((size_t)EG * 64 * sT);
    // union: seg64 (bilinear window) overlaps segN/At1/At2 (atom/out window)
    char* ub  = alloc((size_t)EG * 64 * 4);       // 30.72 MB >= 20.48 MB
    float* seg64 = (float*)ub;
    float* segN  = (float*)ub;
    float* At1   = (float*)(ub + (size_t)NATOM * 256 * 4);
    float* At2   = (float*)(ub + (size_t)NATOM * 256 * 4 + (size_t)NATOM * 128 * 4);
    float* wc_mlp  = (float*)alloc(16 * 256 * 4);
    float* wc_atom = (float*)alloc(16 * 256 * 4);
    float* wc_ob   = (float*)alloc(16 * 256 * 4);
    if (off > ws_size) return false;
    float* out = (float*)d_out;

    // GEMM launchers
    auto gTT = [&](int epi, const T* A, const float* Bw, T* C, const T* skip,
                   int M, int Nn, int Kk) {
        dim3 grid(Nn / 64, (M + 63) / 64);
        if (epi == 1)
            gemm64<T, T, 0, 1><<<grid, 256, 0, stream>>>(A, Bw, C, skip, M, Nn, Kk, nullptr, nullptr, nullptr, nullptr, 0, nullptr);
        else
            gemm64<T, T, 0, 2><<<grid, 256, 0, stream>>>(A, Bw, C, skip, M, Nn, Kk, nullptr, nullptr, nullptr, nullptr, 0, nullptr);
    };
    auto gFT = [&](int epi, const float* A, const float* Bw, T* C,
                   int M, int Nn, int Kk, const int* swp) {
        dim3 grid(Nn / 64, (M + 63) / 64);
        if (epi == 1)
            gemm64<float, T, 0, 1><<<grid, 256, 0, stream>>>(A, Bw, C, nullptr, M, Nn, Kk, nullptr, nullptr, nullptr, nullptr, 0, nullptr);
        else
            gemm64<float, T, 0, 3><<<grid, 256, 0, stream>>>(A, Bw, C, nullptr, M, Nn, Kk, nullptr, nullptr, nullptr, nullptr, 0, swp);
    };
    auto gFF = [&](int epi, const float* A, const float* Bw, float* C, const float* skip,
                   int M, int Nn, int Kk) {
        dim3 grid(Nn / 64, (M + 63) / 64);
        if (epi == 1)
            gemm64<float, float, 0, 1><<<grid, 256, 0, stream>>>(A, Bw, C, skip, M, Nn, Kk, nullptr, nullptr, nullptr, nullptr, 0, nullptr);
        else
            gemm64<float, float, 0, 2><<<grid, 256, 0, stream>>>(A, Bw, C, skip, M, Nn, Kk, nullptr, nullptr, nullptr, nullptr, 0, nullptr);
    };
    auto g1 = [&](const float* Bw, T* C, int M, int Nn, int Kk, const T* Xp, int w2) {
        dim3 grid(Nn / 64, (M + 63) / 64);
        gemm64<T, T, 1, 1><<<grid, 256, 0, stream>>>(nullptr, Bw, C, nullptr, M, Nn, Kk, h, idx_s, idx_t, Xp, w2, nullptr);
    };
    auto out_block = [&](int i) {
        k_wcomb<<<1, 256, 0, stream>>>(W_rbf_out, ob_dense_rbf + (size_t)i * 16 * 256, wc_ob);
        hipMemsetAsync(segN, 0, (size_t)NATOM * 256 * 4, stream);
        k_ln_proj_scatter<T><<<EG, 256, 0, stream>>>(m, ln_m_w + (size_t)i * 256, ln_m_b + (size_t)i * 256,
                                                     rbf, wc_ob, idx_t, segN);
        gFF(1, segN, ob_dense1 + (size_t)i * 256 * 128, At1, nullptr, NATOM, 128, 256);
        for (int r = 0; r < 2; r++) {
            const float* W0 = ob_res + ((size_t)i * 2 + r) * 2 * 128 * 128;
            const float* W1 = W0 + 128 * 128;
            gFF(1, At1, W0, At2, nullptr, NATOM, 128, 128);
            gFF(2, At2, W1, At1, At1, NATOM, 128, 128);
        }
        k_ln_acc<<<NATOM, 128, 0, stream>>>(At1, ln_E_w + (size_t)i * 128, ln_E_b + (size_t)i * 128, out);
    };

    hipMemsetAsync(out, 0, (size_t)NATOM * 128 * 4, stream);
    k_rbf<T><<<(EG + 255) / 256, 256, 0, stream>>>(D, W_cbf_down, rbf, rbfW1);
    k_cbf<T><<<(TT + 255) / 256, 256, 0, stream>>>(cosphi, id3_ca, rbfW1, cbf);
    k_hgather<<<(NATOM * 128 + 255) / 256, 256, 0, stream>>>(atom_emb, Z, h);
    g1(W_edge_emb, m, EG, 256, 272, rbf, 16);

    out_block(0);

    for (int i = 0; i < 2; i++) {
        // ---- triplet interaction ----
        gTT(1, m, ib_dense_ca + (size_t)i * 256 * 256, B1, nullptr, EG, 256, 256);      // x_ca_skip
        gTT(1, m, ib_trip_dense_ba + (size_t)i * 256 * 256, B2, nullptr, EG, 256, 256); // x_ba
        k_wcomb<<<1, 256, 0, stream>>>(W_rbf3, ib_trip_mlp_rbf + (size_t)i * 16 * 256, wc_mlp);
        k_mulproj<0, T><<<EG, 256, 0, stream>>>(B2, rbf, wc_mlp, nullptr, B2, nullptr);
        gTT(1, B2, ib_trip_down + (size_t)i * 256 * 64, xtrip, nullptr, EG, 64, 256);   // x_trip
        hipMemsetAsync(seg64, 0, (size_t)EG * 64 * 4, stream);
        k_bilinear<T><<<TT / 64, 256, 0, stream>>>(xtrip, cbf, ib_trip_bilinear + (size_t)i * 64 * 16 * 64,
                                                   id3_ba, id3_ca, seg64);
        gFT(1, seg64, ib_trip_up_ca + (size_t)i * 64 * 256, B2, EG, 256, 64, nullptr);  // x_ca
        gFT(3, seg64, ib_trip_up_ac + (size_t)i * 64 * 256, B2, EG, 256, 64, id_swap);  // B2 = x3
        k_addscale<T><<<(EG * 256 / 4 + 255) / 256, 256, 0, stream>>>(B1, B2, B1, EG * 256 / 4);
        // ---- edge update ----
        {
            const float* W0 = ib_res_before + (size_t)i * 2 * 256 * 256;
            const float* W1 = W0 + 256 * 256;
            gTT(1, B1, W0, B2, nullptr, EG, 256, 256);
            gTT(2, B2, W1, B1, B1, EG, 256, 256);
        }
        k_addscale<T><<<(EG * 256 / 4 + 255) / 256, 256, 0, stream>>>(B1, m, B1, EG * 256 / 4);
        {
            const float* W0 = ib_res_after + (size_t)i * 2 * 256 * 256;
            const float* W1 = W0 + 256 * 256;
            gTT(1, B1, W0, B2, nullptr, EG, 256, 256);
            gTT(2, B2, W1, B1, B1, EG, 256, 256);
        }
        // ---- atom update ----
        k_wcomb<<<1, 256, 0, stream>>>(W_rbf_h, ib_atom_dense_rbf + (size_t)i * 16 * 256, wc_atom);
        hipMemsetAsync(segN, 0, (size_t)NATOM * 256 * 4, stream);
        k_mulproj<1, T><<<EG, 256, 0, stream>>>(B1, rbf, wc_atom, idx_t, nullptr, segN);
        gFF(1, segN, ib_atom_dense1 + (size_t)i * 256 * 128, At1, nullptr, NATOM, 128, 256);
        for (int r = 0; r < 2; r++) {
            const float* W0 = ib_atom_res + ((size_t)i * 2 + r) * 2 * 128 * 128;
            const float* W1 = W0 + 128 * 128;
            gFF(1, At1, W0, At2, nullptr, NATOM, 128, 128);
            gFF(2, At2, W1, At1, At1, NATOM, 128, 128);
        }
        k_addscale<float><<<(NATOM * 128 / 4 + 255) / 256, 256, 0, stream>>>(h, At1, h, NATOM * 128 / 4);
        // ---- edge embedding refresh ----
        g1(ib_concat_dense + (size_t)i * 512 * 256, B2, EG, 256, 512, B1, 256);
        {
            const float* W0 = ib_res_m + (size_t)i * 2 * 256 * 256;
            const float* W1 = W0 + 256 * 256;
            gTT(1, B2, W0, B1, nullptr, EG, 256, 256);
            gTT(2, B1, W1, B2, B2, EG, 256, 256);
        }
        k_addscale<T><<<(EG * 256 / 4 + 255) / 256, 256, 0, stream>>>(m, B2, m, EG * 256 / 4);

        out_block(i + 1);
    }
    return true;
}

extern "C" void kernel_launch(void* const* d_in, const int* in_sizes, int n_in,
                              void* d_out, int out_size, void* d_ws, size_t ws_size,
                              hipStream_t stream)
{
    if (try_run<bf16t>(d_in, d_out, d_ws, ws_size, stream)) return;
    // still doesn't fit: encode ws_size (MiB) as 3000+MB sentinel.
    float v = 3000.0f + (float)(ws_size >> 20);
    k_fill<<<(NATOM * 128 + 255) / 256, 256, 0, stream>>>((float*)d_out, NATOM * 128, v);
}

// Round 5
// 5469.225 us; speedup vs baseline: 1.4874x; 1.4874x over previous
//
#include <hip/hip_runtime.h>

#define NATOM 10000
#define EG    120000
#define TT    600000

#define INV_SQRT2f 0.7071067811865476f

typedef unsigned short bf16t;
typedef __attribute__((ext_vector_type(8))) short s16x8;
typedef __attribute__((ext_vector_type(8))) unsigned short u16x8;
typedef __attribute__((ext_vector_type(4))) float f32x4;

__device__ __forceinline__ float ssilu(float x) {
    return x * (1.0f / (1.0f + __expf(-x))) * (1.0f / 0.6f);
}
__device__ __forceinline__ float bf2f(unsigned short u) {
    return __uint_as_float(((unsigned)u) << 16);
}
__device__ __forceinline__ unsigned short f2bf(float f) {
    unsigned b = __float_as_uint(f);
    unsigned r = (b + 0x7FFF + ((b >> 16) & 1)) >> 16;  // RNE
    return (unsigned short)r;
}
__device__ __forceinline__ u16x8 cvt8(const float4 va, const float4 vb) {
    u16x8 r{};
    r[0] = f2bf(va.x); r[1] = f2bf(va.y); r[2] = f2bf(va.z); r[3] = f2bf(va.w);
    r[4] = f2bf(vb.x); r[5] = f2bf(vb.y); r[6] = f2bf(vb.z); r[7] = f2bf(vb.w);
    return r;
}

template <typename T> struct VT;
template <> struct VT<float> {
    static __device__ __forceinline__ float4 load4(const float* p) { return *(const float4*)p; }
    static __device__ __forceinline__ void store4(float* p, float4 v) { *(float4*)p = v; }
    static __device__ __forceinline__ float load(const float* p) { return *p; }
    static __device__ __forceinline__ void store(float* p, float v) { *p = v; }
};
template <> struct VT<bf16t> {
    static __device__ __forceinline__ float4 load4(const bf16t* p) {
        ushort4 u = *(const ushort4*)p;
        return make_float4(bf2f(u.x), bf2f(u.y), bf2f(u.z), bf2f(u.w));
    }
    static __device__ __forceinline__ void store4(bf16t* p, float4 v) {
        ushort4 u; u.x = f2bf(v.x); u.y = f2bf(v.y); u.z = f2bf(v.z); u.w = f2bf(v.w);
        *(ushort4*)p = u;
    }
    static __device__ __forceinline__ float load(const bf16t* p) { return bf2f(*p); }
    static __device__ __forceinline__ void store(bf16t* p, float v) { *p = f2bf(v); }
};

// ---------------------------------------------------------------------------
__global__ __launch_bounds__(256) void k_fill(float* __restrict__ o, int n, float v) {
    int i = blockIdx.x * 256 + threadIdx.x;
    if (i < n) o[i] = v;
}

// ---------------------------------------------------------------------------
// combined weight: Wc[16,256] = Wa[16,16] @ Wb[16,256]
// ---------------------------------------------------------------------------
__global__ __launch_bounds__(256) void k_wcomb(
    const float* __restrict__ Wa, const float* __restrict__ Wb, float* __restrict__ Wc)
{
    __shared__ float sA[256];
    int j = threadIdx.x;
    sA[j] = Wa[j];
    __syncthreads();
#pragma unroll 4
    for (int r = 0; r < 16; r++) {
        float acc = 0.f;
#pragma unroll
        for (int k = 0; k < 16; k++) acc = fmaf(sA[r * 16 + k], Wb[k * 256 + j], acc);
        Wc[r * 256 + j] = acc;
    }
}

// ---------------------------------------------------------------------------
// rbf basis + rbf_W1 (cbf down-projection)
// ---------------------------------------------------------------------------
template <typename T>
__global__ __launch_bounds__(256) void k_rbf(
    const float* __restrict__ D, const float* __restrict__ Wc,
    T* __restrict__ rbf, float* __restrict__ rbfW1)
{
    __shared__ float sW[1792];
    for (int i = threadIdx.x; i < 1792; i += 256) sW[i] = Wc[i];
    __syncthreads();
    int e = blockIdx.x * 256 + threadIdx.x;
    if (e >= EG) return;
    float d = D[e] * (1.0f / 6.0f);
    float d2 = d * d, d4 = d2 * d2, d5 = d4 * d, d6 = d5 * d, d7 = d6 * d;
    float env = 1.0f - 21.0f * d5 + 35.0f * d6 - 15.0f * d7;
    if (d >= 1.0f) env = 0.0f;
    float r[16];
#pragma unroll
    for (int i = 0; i < 16; i++) {
        float t = d - (float)i * (1.0f / 15.0f);
        r[i] = env * __expf(-112.5f * t * t);
    }
#pragma unroll
    for (int j = 0; j < 16; j++) VT<T>::store(rbf + (size_t)e * 16 + j, r[j]);
    for (int s = 0; s < 7; s++) {
#pragma unroll 4
        for (int i = 0; i < 16; i++) {
            float a = 0.f;
#pragma unroll
            for (int k = 0; k < 16; k++)
                a = fmaf(r[k], sW[(s * 16 + k) * 16 + i], a);
            rbfW1[(size_t)e * 112 + s * 16 + i] = a;
        }
    }
}

// ---------------------------------------------------------------------------
// spherical basis + cbf_t
// ---------------------------------------------------------------------------
template <typename T>
__global__ __launch_bounds__(256) void k_cbf(
    const float* __restrict__ cosphi, const int* __restrict__ id3_ca,
    const float* __restrict__ rbfW1, T* __restrict__ cbf)
{
    int t = blockIdx.x * 256 + threadIdx.x;
    if (t >= TT) return;
    float c = cosphi[t];
    const float norm[7] = {0.28209479177387814f, 0.4886025119029199f, 0.6307831305050401f,
                           0.7463526651802308f, 0.8462843753216345f, 0.935414346693485f,
                           1.0171072362820548f};
    float y[7];
    float pm2 = 1.0f, pm1 = c;
    y[0] = norm[0];
    y[1] = norm[1] * c;
    for (int l = 2; l < 7; l++) {
        float p = ((2.0f * l - 1.0f) * c * pm1 - (l - 1.0f) * pm2) / (float)l;
        y[l] = norm[l] * p;
        pm2 = pm1; pm1 = p;
    }
    int e = id3_ca[t];
    const float* __restrict__ w = rbfW1 + (size_t)e * 112;
    float out[16];
#pragma unroll
    for (int i = 0; i < 16; i++) out[i] = 0.f;
#pragma unroll
    for (int s = 0; s < 7; s++) {
        float ys = y[s];
#pragma unroll
        for (int i = 0; i < 16; i++) out[i] = fmaf(ys, w[s * 16 + i], out[i]);
    }
#pragma unroll
    for (int i = 0; i < 16; i += 4)
        VT<T>::store4(cbf + (size_t)t * 16 + i, make_float4(out[i], out[i + 1], out[i + 2], out[i + 3]));
}

// ---------------------------------------------------------------------------
__global__ __launch_bounds__(256) void k_hgather(
    const float* __restrict__ emb, const int* __restrict__ Z, float* __restrict__ h)
{
    int i = blockIdx.x * 256 + threadIdx.x;
    if (i < NATOM * 128) {
        int n = i >> 7, j = i & 127;
        h[i] = emb[(size_t)Z[n] * 128 + j];
    }
}

// ---------------------------------------------------------------------------
// MFMA bf16 GEMM: C[M,N](bf16) = epi(A[M,K] @ B[K,N]); B is f32 weights.
// Tile 128x64, BK=32, 4 waves (each 32 rows x 64 cols = 2x4 fragments).
// AMODE 0: plain A (TA bf16 or f32); AMODE 1: A row = concat(h[gS],h[gT],X)
// EPI 1: ssilu; 2: (skip+ssilu)*inv2; 3: C[swp[r]]=(C[swp[r]]+ssilu)*inv2
// ---------------------------------------------------------------------------
template <typename TA, int AMODE, int EPI>
__global__ __launch_bounds__(256) void mgemm(
    const TA* __restrict__ A, const float* __restrict__ B,
    bf16t* __restrict__ C, const bf16t* __restrict__ skip,
    int M, int N, int K,
    const float* __restrict__ hA, const int* __restrict__ gS,
    const int* __restrict__ gT, const bf16t* __restrict__ X, int w2,
    const int* __restrict__ swp)
{
    __shared__ __align__(16) ushort As[128][40];
    __shared__ __align__(16) ushort Bs[64][40];
    const int tid = threadIdx.x;
    const int wave = tid >> 6, lane = tid & 63;
    const int rowBase = blockIdx.y * 128, colBase = blockIdx.x * 64;

    const int ar = tid >> 1;             // 0..127 (A staging row)
    const int ah = (tid & 1) << 4;       // k-half: 0 or 16
    const int arow = rowBase + ar;
    const int arowC = arow < M ? arow : (M - 1);
    int ia = 0, ibx = 0;
    if (AMODE == 1) { ia = gS[arowC]; ibx = gT[arowC]; }

    const int bcol = tid & 63;           // B staging col
    const int bk0 = (tid >> 6) << 3;     // 0,8,16,24

    f32x4 zv = {0.f, 0.f, 0.f, 0.f};
    f32x4 acc[2][4];
#pragma unroll
    for (int p = 0; p < 2; p++)
#pragma unroll
        for (int q = 0; q < 4; q++) acc[p][q] = zv;

    const ushort* asBase = &As[0][0];
    const ushort* bsBase = &Bs[0][0];
    const int aoff = (wave * 32 + (lane & 15)) * 40 + ((lane >> 4) << 3);
    const int boff = (lane & 15) * 40 + ((lane >> 4) << 3);

    for (int k0 = 0; k0 < K; k0 += 32) {
        u16x8 a0{}, a1{};
        const int kk = k0 + ah;
        if (AMODE == 0) {
            if (kk < K) {
                if constexpr (sizeof(TA) == 2) {
                    const u16x8* s = (const u16x8*)((const bf16t*)A + (size_t)arowC * K + kk);
                    a0 = s[0]; a1 = s[1];
                } else {
                    const float4* s = (const float4*)((const float*)A + (size_t)arowC * K + kk);
                    a0 = cvt8(s[0], s[1]); a1 = cvt8(s[2], s[3]);
                }
            }
        } else {
            if (kk < 128) {
                const float4* s = (const float4*)(hA + (size_t)ia * 128 + kk);
                a0 = cvt8(s[0], s[1]); a1 = cvt8(s[2], s[3]);
            } else if (kk < 256) {
                const float4* s = (const float4*)(hA + (size_t)ibx * 128 + (kk - 128));
                a0 = cvt8(s[0], s[1]); a1 = cvt8(s[2], s[3]);
            } else if (kk - 256 < w2) {
                const u16x8* s = (const u16x8*)(X + (size_t)arowC * w2 + (kk - 256));
                a0 = s[0]; a1 = s[1];
            }
        }
        ushort bvals[8];
#pragma unroll
        for (int j = 0; j < 8; j++) {
            int k = k0 + bk0 + j;
            bvals[j] = (k < K) ? f2bf(B[(size_t)k * N + colBase + bcol]) : (ushort)0;
        }
        __syncthreads();
        *(u16x8*)&As[ar][ah] = a0;
        *(u16x8*)&As[ar][ah + 8] = a1;
#pragma unroll
        for (int j = 0; j < 8; j++) Bs[bcol][bk0 + j] = bvals[j];
        __syncthreads();

        u16x8 af0 = *(const u16x8*)(asBase + aoff);
        u16x8 af1 = *(const u16x8*)(asBase + aoff + 16 * 40);
#pragma unroll
        for (int fc = 0; fc < 4; fc++) {
            u16x8 bf = *(const u16x8*)(bsBase + boff + fc * 16 * 40);
            acc[0][fc] = __builtin_amdgcn_mfma_f32_16x16x32_bf16(
                *(s16x8*)&af0, *(s16x8*)&bf, acc[0][fc], 0, 0, 0);
            acc[1][fc] = __builtin_amdgcn_mfma_f32_16x16x32_bf16(
                *(s16x8*)&af1, *(s16x8*)&bf, acc[1][fc], 0, 0, 0);
        }
    }

    const int rBase = rowBase + wave * 32 + ((lane >> 4) << 2);
    const int cBase = colBase + (lane & 15);
#pragma unroll
    for (int fr = 0; fr < 2; fr++) {
#pragma unroll
        for (int r = 0; r < 4; r++) {
            int row = rBase + fr * 16 + r;
            if (row >= M) continue;
#pragma unroll
            for (int fc = 0; fc < 4; fc++) {
                int col = cBase + fc * 16;
                float v = acc[fr][fc][r];
                if (EPI == 1) {
                    C[(size_t)row * N + col] = f2bf(ssilu(v));
                } else if (EPI == 2) {
                    float sk = bf2f(skip[(size_t)row * N + col]);
                    C[(size_t)row * N + col] = f2bf((sk + ssilu(v)) * INV_SQRT2f);
                } else {
                    int tr = swp[row];
                    bf16t* cp = &C[(size_t)tr * N + col];
                    *cp = f2bf((bf2f(*cp) + ssilu(v)) * INV_SQRT2f);
                }
            }
        }
    }
}

// ---------------------------------------------------------------------------
// MFMA bilinear: seg[id3_ca[t]] += sum_i cbf[t,i] * (xt[id3_ba[t]] @ W_i)
// Per block: 64 triplets. Loop i: stage W_i^T bf16, P_i via MFMA, scale+acc.
// ---------------------------------------------------------------------------
__global__ __launch_bounds__(256) void k_bilinear_m(
    const bf16t* __restrict__ xtrip, const bf16t* __restrict__ cbf,
    const float* __restrict__ Wb,
    const int* __restrict__ id3_ba, const int* __restrict__ id3_ca,
    float* __restrict__ seg)
{
    __shared__ __align__(16) ushort xs[64][72];
    __shared__ __align__(16) ushort ws[64][72];
    __shared__ ushort cbs[64][16];
    __shared__ int cas[64];
    const int tid = threadIdx.x, wave = tid >> 6, lane = tid & 63;
    const int t0 = blockIdx.x * 64;
    {
        int r = tid >> 2, q = (tid & 3) << 4;
        int ba = id3_ba[t0 + r];
        const u16x8* src = (const u16x8*)(xtrip + (size_t)ba * 64 + q);
        *(u16x8*)&xs[r][q] = src[0];
        *(u16x8*)&xs[r][q + 8] = src[1];
    }
    if (tid < 64) cas[tid] = id3_ca[t0 + tid];
    {
        int e = tid << 2; int r = e >> 4, c = e & 15;
        *(ushort4*)&cbs[r][c] = *(const ushort4*)(cbf + (size_t)(t0 + r) * 16 + c);
    }
    const ushort* xsBase = &xs[0][0];
    const ushort* wsBase = &ws[0][0];
    const int axoff = (wave * 16 + (lane & 15)) * 72 + ((lane >> 4) << 3);
    const int bxoff = (lane & 15) * 72 + ((lane >> 4) << 3);
    const int wo = tid & 63;
    const int wc0 = (tid >> 6) << 4;
    float tot[4][4];
#pragma unroll
    for (int a = 0; a < 4; a++)
#pragma unroll
        for (int b = 0; b < 4; b++) tot[a][b] = 0.f;

    for (int i = 0; i < 16; i++) {
        __syncthreads();  // also covers initial xs/cbs/cas staging on i==0
#pragma unroll 4
        for (int j = 0; j < 16; j++) {
            int c = wc0 + j;
            ws[wo][c] = f2bf(Wb[(size_t)(c * 16 + i) * 64 + wo]);
        }
        __syncthreads();
        f32x4 zv = {0.f, 0.f, 0.f, 0.f};
        f32x4 p[4] = {zv, zv, zv, zv};
#pragma unroll
        for (int k0 = 0; k0 < 64; k0 += 32) {
            u16x8 a = *(const u16x8*)(xsBase + axoff + k0);
#pragma unroll
            for (int fc = 0; fc < 4; fc++) {
                u16x8 b = *(const u16x8*)(wsBase + bxoff + fc * 16 * 72 + k0);
                p[fc] = __builtin_amdgcn_mfma_f32_16x16x32_bf16(
                    *(s16x8*)&a, *(s16x8*)&b, p[fc], 0, 0, 0);
            }
        }
#pragma unroll
        for (int r = 0; r < 4; r++) {
            int row = wave * 16 + ((lane >> 4) << 2) + r;
            float s = bf2f(cbs[row][i]);
#pragma unroll
            for (int fc = 0; fc < 4; fc++) tot[fc][r] += s * p[fc][r];
        }
    }
#pragma unroll
    for (int r = 0; r < 4; r++) {
        int row = wave * 16 + ((lane >> 4) << 2) + r;
        int ca = cas[row];
#pragma unroll
        for (int fc = 0; fc < 4; fc++) {
            int col = fc * 16 + (lane & 15);
            atomicAdd(&seg[(size_t)ca * 64 + col], tot[fc][r]);
        }
    }
}

// ---------------------------------------------------------------------------
// f32 VALU GEMM (kept for small NATOM-sized GEMMs on the output path)
// ---------------------------------------------------------------------------
template <typename TA, typename TC, int AMODE, int EPI>
__global__ __launch_bounds__(256) void gemm64(
    const TA* __restrict__ A, const float* __restrict__ B,
    TC* __restrict__ C, const TC* __restrict__ skip,
    int M, int N, int K,
    const float* __restrict__ hA, const int* __restrict__ gS,
    const int* __restrict__ gT, const TA* __restrict__ X, int w2,
    const int* __restrict__ swp)
{
    __shared__ __align__(16) float As[16][64];
    __shared__ __align__(16) float Bs[16][64];
    const int tid = threadIdx.x;
    const int tx = tid & 15, ty = tid >> 4;
    const int rowBase = blockIdx.y * 64;
    const int colBase = blockIdx.x * 64;
    const int lr = tid >> 2;
    const int lk = (tid & 3) * 4;
    const int bk = tid >> 4;
    const int bc = (tid & 15) * 4;
    int arow = rowBase + lr;
    int arowC = arow < M ? arow : (M - 1);

    float acc[4][4];
#pragma unroll
    for (int i = 0; i < 4; i++)
#pragma unroll
        for (int j = 0; j < 4; j++) acc[i][j] = 0.f;

    for (int k0 = 0; k0 < K; k0 += 16) {
        float4 a4, b4;
        a4 = VT<TA>::load4(A + (size_t)arowC * K + k0 + lk);
        b4 = *(const float4*)(B + (size_t)(k0 + bk) * N + colBase + bc);
        __syncthreads();
        As[lk + 0][lr] = a4.x;
        As[lk + 1][lr] = a4.y;
        As[lk + 2][lr] = a4.z;
        As[lk + 3][lr] = a4.w;
        *(float4*)(&Bs[bk][bc]) = b4;
        __syncthreads();
#pragma unroll
        for (int kk = 0; kk < 16; kk++) {
            float4 av = *(const float4*)(&As[kk][ty * 4]);
            float4 bv = *(const float4*)(&Bs[kk][tx * 4]);
            float a[4] = {av.x, av.y, av.z, av.w};
            float b[4] = {bv.x, bv.y, bv.z, bv.w};
#pragma unroll
            for (int i = 0; i < 4; i++)
#pragma unroll
                for (int j = 0; j < 4; j++)
                    acc[i][j] = fmaf(a[i], b[j], acc[i][j]);
        }
    }
    const int col0 = colBase + tx * 4;
#pragma unroll
    for (int ri = 0; ri < 4; ri++) {
        int row = rowBase + ty * 4 + ri;
        if (row >= M) break;
        TC* cp = C + (size_t)row * N + col0;
#pragma unroll
        for (int ci = 0; ci < 4; ci++) {
            float v = acc[ri][ci];
            if (EPI == 1) v = ssilu(v);
            if (EPI == 2) v = (VT<TC>::load(skip + (size_t)row * N + col0 + ci) + ssilu(v)) * INV_SQRT2f;
            VT<TC>::store(cp + ci, v);
        }
    }
}

// ---------------------------------------------------------------------------
// per-edge multiply by (rbf[e,16] @ Wc[16,256]); SCATTER: atomicAdd f32 to idxT
// ---------------------------------------------------------------------------
template <int SCATTER, typename T>
__global__ __launch_bounds__(256) void k_mulproj(
    const T* __restrict__ in, const T* __restrict__ rvec,
    const float* __restrict__ Wp, const int* __restrict__ idxT,
    T* __restrict__ out, float* __restrict__ outf)
{
    int e = blockIdx.x;
    int j = threadIdx.x;
    __shared__ float r16[16];
    if (j < 16) r16[j] = VT<T>::load(rvec + (size_t)e * 16 + j);
    __syncthreads();
    float p = 0.f;
#pragma unroll
    for (int k = 0; k < 16; k++) p = fmaf(r16[k], Wp[k * 256 + j], p);
    float v = VT<T>::load(in + (size_t)e * 256 + j) * p;
    if (SCATTER) atomicAdd(&outf[(size_t)idxT[e] * 256 + j], v);
    else VT<T>::store(out + (size_t)e * 256 + j, v);
}

// ---------------------------------------------------------------------------
// LN(m row) * (rbf[e,16] @ Wc[16,256]) scattered into segN (f32) by idx_t
// ---------------------------------------------------------------------------
template <typename T>
__global__ __launch_bounds__(256) void k_ln_proj_scatter(
    const T* __restrict__ m, const float* __restrict__ lnw,
    const float* __restrict__ lnb, const T* __restrict__ rvec,
    const float* __restrict__ Wp, const int* __restrict__ idxT,
    float* __restrict__ segN)
{
    int e = blockIdx.x;
    int j = threadIdx.x;
    __shared__ float red[8];
    __shared__ float r16[16];
    if (j < 16) r16[j] = VT<T>::load(rvec + (size_t)e * 16 + j);
    float v = VT<T>::load(m + (size_t)e * 256 + j);
    float s = v, s2 = v * v;
#pragma unroll
    for (int off = 32; off > 0; off >>= 1) {
        s += __shfl_xor(s, off);
        s2 += __shfl_xor(s2, off);
    }
    int wid = j >> 6, lane = j & 63;
    if (lane == 0) { red[wid] = s; red[4 + wid] = s2; }
    __syncthreads();
    float tot = red[0] + red[1] + red[2] + red[3];
    float tot2 = red[4] + red[5] + red[6] + red[7];
    float mu = tot * (1.f / 256.f);
    float var = tot2 * (1.f / 256.f) - mu * mu;
    float ln = (v - mu) * rsqrtf(var + 1e-5f) * lnw[j] + lnb[j];
    float p = 0.f;
#pragma unroll
    for (int k = 0; k < 16; k++) p = fmaf(r16[k], Wp[k * 256 + j], p);
    atomicAdd(&segN[(size_t)idxT[e] * 256 + j], ln * p);
}

// ---------------------------------------------------------------------------
__global__ __launch_bounds__(128) void k_ln_acc(
    const float* __restrict__ x, const float* __restrict__ w,
    const float* __restrict__ b, float* __restrict__ out)
{
    int n = blockIdx.x;
    int j = threadIdx.x;
    __shared__ float red[4];
    float v = x[(size_t)n * 128 + j];
    float s = v, s2 = v * v;
#pragma unroll
    for (int off = 32; off > 0; off >>= 1) {
        s += __shfl_xor(s, off);
        s2 += __shfl_xor(s2, off);
    }
    int wid = j >> 6, lane = j & 63;
    if (lane == 0) { red[wid] = s; red[2 + wid] = s2; }
    __syncthreads();
    float tot = red[0] + red[1];
    float tot2 = red[2] + red[3];
    float mu = tot * (1.f / 128.f);
    float var = tot2 * (1.f / 128.f) - mu * mu;
    out[(size_t)n * 128 + j] += (v - mu) * rsqrtf(var + 1e-5f) * w[j] + b[j];
}

// ---------------------------------------------------------------------------
template <typename T>
__global__ __launch_bounds__(256) void k_addscale(
    const T* __restrict__ a, const T* __restrict__ b, T* __restrict__ y, int n4)
{
    int i = blockIdx.x * 256 + threadIdx.x;
    if (i < n4) {
        float4 av = VT<T>::load4(a + (size_t)i * 4);
        float4 bv = VT<T>::load4(b + (size_t)i * 4);
        VT<T>::store4(y + (size_t)i * 4,
                      make_float4((av.x + bv.x) * INV_SQRT2f, (av.y + bv.y) * INV_SQRT2f,
                                  (av.z + bv.z) * INV_SQRT2f, (av.w + bv.w) * INV_SQRT2f));
    }
}

// ---------------------------------------------------------------------------
template <typename T>
static bool try_run(void* const* d_in, void* d_out, void* d_ws, size_t ws_size, hipStream_t stream)
{
    const float* D            = (const float*)d_in[0];
    const float* cosphi       = (const float*)d_in[1];
    const float* atom_emb     = (const float*)d_in[2];
    const float* W_rbf3       = (const float*)d_in[3];
    const float* W_rbf_h      = (const float*)d_in[4];
    const float* W_rbf_out    = (const float*)d_in[5];
    const float* W_cbf_down   = (const float*)d_in[6];
    const float* W_edge_emb   = (const float*)d_in[7];
    const float* ib_dense_ca  = (const float*)d_in[8];
    const float* ib_trip_dense_ba = (const float*)d_in[9];
    const float* ib_trip_mlp_rbf  = (const float*)d_in[10];
    const float* ib_trip_down     = (const float*)d_in[11];
    const float* ib_trip_bilinear = (const float*)d_in[12];
    const float* ib_trip_up_ca    = (const float*)d_in[13];
    const float* ib_trip_up_ac    = (const float*)d_in[14];
    const float* ib_res_before    = (const float*)d_in[15];
    const float* ib_res_after     = (const float*)d_in[16];
    const float* ib_atom_dense_rbf = (const float*)d_in[17];
    const float* ib_atom_dense1    = (const float*)d_in[18];
    const float* ib_atom_res       = (const float*)d_in[19];
    const float* ib_concat_dense   = (const float*)d_in[20];
    const float* ib_res_m          = (const float*)d_in[21];
    const float* ob_dense_rbf      = (const float*)d_in[22];
    const float* ob_dense1         = (const float*)d_in[23];
    const float* ob_res            = (const float*)d_in[24];
    const float* ln_m_w            = (const float*)d_in[25];
    const float* ln_m_b            = (const float*)d_in[26];
    const float* ln_E_w            = (const float*)d_in[27];
    const float* ln_E_b            = (const float*)d_in[28];
    const int* Z       = (const int*)d_in[29];
    const int* idx_s   = (const int*)d_in[30];
    const int* idx_t   = (const int*)d_in[31];
    const int* id3_ba  = (const int*)d_in[32];
    const int* id3_ca  = (const int*)d_in[33];
    const int* id_swap = (const int*)d_in[34];

    const size_t sT = sizeof(T);
    char* base = (char*)d_ws;
    size_t off = 0;
    auto alloc = [&](size_t bytes) -> char* {
        off = (off + 255) & ~(size_t)255;
        char* p = base + off;
        off += bytes;
        return p;
    };
    T* m      = (T*)alloc((size_t)EG * 256 * sT);
    T* B1     = (T*)alloc((size_t)EG * 256 * sT);
    T* B2     = (T*)alloc((size_t)EG * 256 * sT);
    float* rbfW1 = (float*)B1;                    // alias: dead before B1 first written
    T* rbf    = (T*)alloc((size_t)EG * 16 * sT);  // persistent basis
    T* cbf    = (T*)alloc((size_t)TT * 16 * sT);
    float* h  = (float*)alloc((size_t)NATOM * 128 * 4);
    T* xtrip  = (T*)alloc((size_t)EG * 64 * sT);
    // union: seg64 (bilinear window) overlaps segN/At1/At2 (atom/out window)
    char* ub  = alloc((size_t)EG * 64 * 4);       // 30.72 MB >= 20.48 MB
    float* seg64 = (float*)ub;
    float* segN  = (float*)ub;
    float* At1   = (float*)(ub + (size_t)NATOM * 256 * 4);
    float* At2   = (float*)(ub + (size_t)NATOM * 256 * 4 + (size_t)NATOM * 128 * 4);
    float* wc_mlp  = (float*)alloc(16 * 256 * 4);
    float* wc_atom = (float*)alloc(16 * 256 * 4);
    float* wc_ob   = (float*)alloc(16 * 256 * 4);
    if (off > ws_size) return false;
    float* out = (float*)d_out;

    // MFMA GEMM launchers (EG-sized)
    auto mTT = [&](int epi, const T* A, const float* Bw, T* C, const T* skip,
                   int M, int Nn, int Kk) {
        dim3 grid(Nn / 64, (M + 127) / 128);
        if (epi == 1)
            mgemm<T, 0, 1><<<grid, 256, 0, stream>>>(A, Bw, C, skip, M, Nn, Kk, nullptr, nullptr, nullptr, nullptr, 0, nullptr);
        else
            mgemm<T, 0, 2><<<grid, 256, 0, stream>>>(A, Bw, C, skip, M, Nn, Kk, nullptr, nullptr, nullptr, nullptr, 0, nullptr);
    };
    auto mFT = [&](int epi, const float* A, const float* Bw, T* C,
                   int M, int Nn, int Kk, const int* swp) {
        dim3 grid(Nn / 64, (M + 127) / 128);
        if (epi == 1)
            mgemm<float, 0, 1><<<grid, 256, 0, stream>>>(A, Bw, C, nullptr, M, Nn, Kk, nullptr, nullptr, nullptr, nullptr, 0, nullptr);
        else
            mgemm<float, 0, 3><<<grid, 256, 0, stream>>>(A, Bw, C, nullptr, M, Nn, Kk, nullptr, nullptr, nullptr, nullptr, 0, swp);
    };
    auto mG1 = [&](const float* Bw, T* C, int M, int Nn, int Kk, const T* Xp, int w2) {
        dim3 grid(Nn / 64, (M + 127) / 128);
        mgemm<T, 1, 1><<<grid, 256, 0, stream>>>(nullptr, Bw, C, nullptr, M, Nn, Kk, h, idx_s, idx_t, Xp, w2, nullptr);
    };
    // f32 VALU GEMM (NATOM-sized, output path)
    auto gFF = [&](int epi, const float* A, const float* Bw, float* C, const float* skip,
                   int M, int Nn, int Kk) {
        dim3 grid(Nn / 64, (M + 63) / 64);
        if (epi == 1)
            gemm64<float, float, 0, 1><<<grid, 256, 0, stream>>>(A, Bw, C, skip, M, Nn, Kk, nullptr, nullptr, nullptr, nullptr, 0, nullptr);
        else
            gemm64<float, float, 0, 2><<<grid, 256, 0, stream>>>(A, Bw, C, skip, M, Nn, Kk, nullptr, nullptr, nullptr, nullptr, 0, nullptr);
    };
    auto out_block = [&](int i) {
        k_wcomb<<<1, 256, 0, stream>>>(W_rbf_out, ob_dense_rbf + (size_t)i * 16 * 256, wc_ob);
        hipMemsetAsync(segN, 0, (size_t)NATOM * 256 * 4, stream);
        k_ln_proj_scatter<T><<<EG, 256, 0, stream>>>(m, ln_m_w + (size_t)i * 256, ln_m_b + (size_t)i * 256,
                                                     rbf, wc_ob, idx_t, segN);
        gFF(1, segN, ob_dense1 + (size_t)i * 256 * 128, At1, nullptr, NATOM, 128, 256);
        for (int r = 0; r < 2; r++) {
            const float* W0 = ob_res + ((size_t)i * 2 + r) * 2 * 128 * 128;
            const float* W1 = W0 + 128 * 128;
            gFF(1, At1, W0, At2, nullptr, NATOM, 128, 128);
            gFF(2, At2, W1, At1, At1, NATOM, 128, 128);
        }
        k_ln_acc<<<NATOM, 128, 0, stream>>>(At1, ln_E_w + (size_t)i * 128, ln_E_b + (size_t)i * 128, out);
    };

    hipMemsetAsync(out, 0, (size_t)NATOM * 128 * 4, stream);
    k_rbf<T><<<(EG + 255) / 256, 256, 0, stream>>>(D, W_cbf_down, rbf, rbfW1);
    k_cbf<T><<<(TT + 255) / 256, 256, 0, stream>>>(cosphi, id3_ca, rbfW1, cbf);
    k_hgather<<<(NATOM * 128 + 255) / 256, 256, 0, stream>>>(atom_emb, Z, h);
    mG1(W_edge_emb, m, EG, 256, 272, rbf, 16);

    out_block(0);

    for (int i = 0; i < 2; i++) {
        // ---- triplet interaction ----
        mTT(1, m, ib_dense_ca + (size_t)i * 256 * 256, B1, nullptr, EG, 256, 256);      // x_ca_skip
        mTT(1, m, ib_trip_dense_ba + (size_t)i * 256 * 256, B2, nullptr, EG, 256, 256); // x_ba
        k_wcomb<<<1, 256, 0, stream>>>(W_rbf3, ib_trip_mlp_rbf + (size_t)i * 16 * 256, wc_mlp);
        k_mulproj<0, T><<<EG, 256, 0, stream>>>(B2, rbf, wc_mlp, nullptr, B2, nullptr);
        mTT(1, B2, ib_trip_down + (size_t)i * 256 * 64, xtrip, nullptr, EG, 64, 256);   // x_trip
        hipMemsetAsync(seg64, 0, (size_t)EG * 64 * 4, stream);
        k_bilinear_m<<<TT / 64, 256, 0, stream>>>(xtrip, cbf, ib_trip_bilinear + (size_t)i * 64 * 16 * 64,
                                                  id3_ba, id3_ca, seg64);
        mFT(1, seg64, ib_trip_up_ca + (size_t)i * 64 * 256, B2, EG, 256, 64, nullptr);  // x_ca
        mFT(3, seg64, ib_trip_up_ac + (size_t)i * 64 * 256, B2, EG, 256, 64, id_swap);  // B2 = x3
        k_addscale<T><<<(EG * 256 / 4 + 255) / 256, 256, 0, stream>>>(B1, B2, B1, EG * 256 / 4);
        // ---- edge update ----
        {
            const float* W0 = ib_res_before + (size_t)i * 2 * 256 * 256;
            const float* W1 = W0 + 256 * 256;
            mTT(1, B1, W0, B2, nullptr, EG, 256, 256);
            mTT(2, B2, W1, B1, B1, EG, 256, 256);
        }
        k_addscale<T><<<(EG * 256 / 4 + 255) / 256, 256, 0, stream>>>(B1, m, B1, EG * 256 / 4);
        {
            const float* W0 = ib_res_after + (size_t)i * 2 * 256 * 256;
            const float* W1 = W0 + 256 * 256;
            mTT(1, B1, W0, B2, nullptr, EG, 256, 256);
            mTT(2, B2, W1, B1, B1, EG, 256, 256);
        }
        // ---- atom update ----
        k_wcomb<<<1, 256, 0, stream>>>(W_rbf_h, ib_atom_dense_rbf + (size_t)i * 16 * 256, wc_atom);
        hipMemsetAsync(segN, 0, (size_t)NATOM * 256 * 4, stream);
        k_mulproj<1, T><<<EG, 256, 0, stream>>>(B1, rbf, wc_atom, idx_t, nullptr, segN);
        gFF(1, segN, ib_atom_dense1 + (size_t)i * 256 * 128, At1, nullptr, NATOM, 128, 256);
        for (int r = 0; r < 2; r++) {
            const float* W0 = ib_atom_res + ((size_t)i * 2 + r) * 2 * 128 * 128;
            const float* W1 = W0 + 128 * 128;
            gFF(1, At1, W0, At2, nullptr, NATOM, 128, 128);
            gFF(2, At2, W1, At1, At1, NATOM, 128, 128);
        }
        k_addscale<float><<<(NATOM * 128 / 4 + 255) / 256, 256, 0, stream>>>(h, At1, h, NATOM * 128 / 4);
        // ---- edge embedding refresh ----
        mG1(ib_concat_dense + (size_t)i * 512 * 256, B2, EG, 256, 512, B1, 256);
        {
            const float* W0 = ib_res_m + (size_t)i * 2 * 256 * 256;
            const float* W1 = W0 + 256 * 256;
            mTT(1, B2, W0, B1, nullptr, EG, 256, 256);
            mTT(2, B1, W1, B2, B2, EG, 256, 256);
        }
        k_addscale<T><<<(EG * 256 / 4 + 255) / 256, 256, 0, stream>>>(m, B2, m, EG * 256 / 4);

        out_block(i + 1);
    }
    return true;
}

extern "C" void kernel_launch(void* const* d_in, const int* in_sizes, int n_in,
                              void* d_out, int out_size, void* d_ws, size_t ws_size,
                              hipStream_t stream)
{
    if (try_run<bf16t>(d_in, d_out, d_ws, ws_size, stream)) return;
    float v = 3000.0f + (float)(ws_size >> 20);
    k_fill<<<(NATOM * 128 + 255) / 256, 256, 0, stream>>>((float*)d_out, NATOM * 128, v);
}

// Round 6
// 4649.303 us; speedup vs baseline: 1.7497x; 1.1764x over previous
//
#include <hip/hip_runtime.h>

#define NATOM 10000
#define EG    120000
#define TT    600000

#define INV_SQRT2f 0.7071067811865476f

typedef unsigned short bf16t;
typedef __attribute__((ext_vector_type(8))) short s16x8;
typedef __attribute__((ext_vector_type(8))) unsigned short u16x8;
typedef __attribute__((ext_vector_type(4))) float f32x4;

__device__ __forceinline__ float ssilu(float x) {
    return x * (1.0f / (1.0f + __expf(-x))) * (1.0f / 0.6f);
}
__device__ __forceinline__ float bf2f(unsigned short u) {
    return __uint_as_float(((unsigned)u) << 16);
}
__device__ __forceinline__ unsigned short f2bf(float f) {
    unsigned b = __float_as_uint(f);
    unsigned r = (b + 0x7FFF + ((b >> 16) & 1)) >> 16;  // RNE
    return (unsigned short)r;
}
__device__ __forceinline__ u16x8 cvt8(const float4 va, const float4 vb) {
    u16x8 r{};
    r[0] = f2bf(va.x); r[1] = f2bf(va.y); r[2] = f2bf(va.z); r[3] = f2bf(va.w);
    r[4] = f2bf(vb.x); r[5] = f2bf(vb.y); r[6] = f2bf(vb.z); r[7] = f2bf(vb.w);
    return r;
}

template <typename T> struct VT;
template <> struct VT<float> {
    static __device__ __forceinline__ float4 load4(const float* p) { return *(const float4*)p; }
    static __device__ __forceinline__ void store4(float* p, float4 v) { *(float4*)p = v; }
    static __device__ __forceinline__ float load(const float* p) { return *p; }
    static __device__ __forceinline__ void store(float* p, float v) { *p = v; }
};
template <> struct VT<bf16t> {
    static __device__ __forceinline__ float4 load4(const bf16t* p) {
        ushort4 u = *(const ushort4*)p;
        return make_float4(bf2f(u.x), bf2f(u.y), bf2f(u.z), bf2f(u.w));
    }
    static __device__ __forceinline__ void store4(bf16t* p, float4 v) {
        ushort4 u; u.x = f2bf(v.x); u.y = f2bf(v.y); u.z = f2bf(v.z); u.w = f2bf(v.w);
        *(ushort4*)p = u;
    }
    static __device__ __forceinline__ float load(const bf16t* p) { return bf2f(*p); }
    static __device__ __forceinline__ void store(bf16t* p, float v) { *p = f2bf(v); }
};

// ---------------------------------------------------------------------------
__global__ __launch_bounds__(256) void k_fill(float* __restrict__ o, int n, float v) {
    int i = blockIdx.x * 256 + threadIdx.x;
    if (i < n) o[i] = v;
}

// ---------------------------------------------------------------------------
// weight transpose+convert: BT[n][k] (bf16, K padded to KP) from B[k][n] f32
// ---------------------------------------------------------------------------
__global__ __launch_bounds__(256) void k_wt(
    const float* __restrict__ B, bf16t* __restrict__ BT, int K, int KP, int N)
{
    int idx = blockIdx.x * 256 + threadIdx.x;
    if (idx >= N * KP) return;
    int n = idx / KP, k = idx - n * KP;
    BT[idx] = (k < K) ? f2bf(B[(size_t)k * N + n]) : (bf16t)0;
}

// bilinear weight: WT[i][o][c] bf16 from Wb[c][i][o] f32 (c=64,i=16,o=64)
__global__ __launch_bounds__(256) void k_wtb(
    const float* __restrict__ Wb, bf16t* __restrict__ WT)
{
    int idx = blockIdx.x * 256 + threadIdx.x;
    if (idx >= 16 * 64 * 64) return;
    int i = idx >> 12, o = (idx >> 6) & 63, c = idx & 63;
    WT[idx] = f2bf(Wb[((size_t)c * 16 + i) * 64 + o]);
}

// ---------------------------------------------------------------------------
// combined weight: Wc[16,256] = Wa[16,16] @ Wb[16,256]
// ---------------------------------------------------------------------------
__global__ __launch_bounds__(256) void k_wcomb(
    const float* __restrict__ Wa, const float* __restrict__ Wb, float* __restrict__ Wc)
{
    __shared__ float sA[256];
    int j = threadIdx.x;
    sA[j] = Wa[j];
    __syncthreads();
#pragma unroll 4
    for (int r = 0; r < 16; r++) {
        float acc = 0.f;
#pragma unroll
        for (int k = 0; k < 16; k++) acc = fmaf(sA[r * 16 + k], Wb[k * 256 + j], acc);
        Wc[r * 256 + j] = acc;
    }
}

// ---------------------------------------------------------------------------
// rbf basis + rbf_W1 (cbf down-projection)
// ---------------------------------------------------------------------------
template <typename T>
__global__ __launch_bounds__(256) void k_rbf(
    const float* __restrict__ D, const float* __restrict__ Wc,
    T* __restrict__ rbf, float* __restrict__ rbfW1)
{
    __shared__ float sW[1792];
    for (int i = threadIdx.x; i < 1792; i += 256) sW[i] = Wc[i];
    __syncthreads();
    int e = blockIdx.x * 256 + threadIdx.x;
    if (e >= EG) return;
    float d = D[e] * (1.0f / 6.0f);
    float d2 = d * d, d4 = d2 * d2, d5 = d4 * d, d6 = d5 * d, d7 = d6 * d;
    float env = 1.0f - 21.0f * d5 + 35.0f * d6 - 15.0f * d7;
    if (d >= 1.0f) env = 0.0f;
    float r[16];
#pragma unroll
    for (int i = 0; i < 16; i++) {
        float t = d - (float)i * (1.0f / 15.0f);
        r[i] = env * __expf(-112.5f * t * t);
    }
#pragma unroll
    for (int j = 0; j < 16; j++) VT<T>::store(rbf + (size_t)e * 16 + j, r[j]);
    for (int s = 0; s < 7; s++) {
#pragma unroll 4
        for (int i = 0; i < 16; i++) {
            float a = 0.f;
#pragma unroll
            for (int k = 0; k < 16; k++)
                a = fmaf(r[k], sW[(s * 16 + k) * 16 + i], a);
            rbfW1[(size_t)e * 112 + s * 16 + i] = a;
        }
    }
}

// ---------------------------------------------------------------------------
// spherical basis + cbf_t
// ---------------------------------------------------------------------------
template <typename T>
__global__ __launch_bounds__(256) void k_cbf(
    const float* __restrict__ cosphi, const int* __restrict__ id3_ca,
    const float* __restrict__ rbfW1, T* __restrict__ cbf)
{
    int t = blockIdx.x * 256 + threadIdx.x;
    if (t >= TT) return;
    float c = cosphi[t];
    const float norm[7] = {0.28209479177387814f, 0.4886025119029199f, 0.6307831305050401f,
                           0.7463526651802308f, 0.8462843753216345f, 0.935414346693485f,
                           1.0171072362820548f};
    float y[7];
    float pm2 = 1.0f, pm1 = c;
    y[0] = norm[0];
    y[1] = norm[1] * c;
    for (int l = 2; l < 7; l++) {
        float p = ((2.0f * l - 1.0f) * c * pm1 - (l - 1.0f) * pm2) / (float)l;
        y[l] = norm[l] * p;
        pm2 = pm1; pm1 = p;
    }
    int e = id3_ca[t];
    const float* __restrict__ w = rbfW1 + (size_t)e * 112;
    float out[16];
#pragma unroll
    for (int i = 0; i < 16; i++) out[i] = 0.f;
#pragma unroll
    for (int s = 0; s < 7; s++) {
        float ys = y[s];
#pragma unroll
        for (int i = 0; i < 16; i++) out[i] = fmaf(ys, w[s * 16 + i], out[i]);
    }
#pragma unroll
    for (int i = 0; i < 16; i += 4)
        VT<T>::store4(cbf + (size_t)t * 16 + i, make_float4(out[i], out[i + 1], out[i + 2], out[i + 3]));
}

// ---------------------------------------------------------------------------
__global__ __launch_bounds__(256) void k_hgather(
    const float* __restrict__ emb, const int* __restrict__ Z, float* __restrict__ h)
{
    int i = blockIdx.x * 256 + threadIdx.x;
    if (i < NATOM * 128) {
        int n = i >> 7, j = i & 127;
        h[i] = emb[(size_t)Z[n] * 128 + j];
    }
}

// ---------------------------------------------------------------------------
// mgemm2: barrier-free MFMA GEMM. C[M,N](bf16) = epi(A[M,K] @ BT^T)
// BT is [N][K] bf16 (pre-transposed weights). Tile 128 x (FC*16), 4 waves.
// A fragments direct from global (bf16 or f32 rows). No LDS.
// EPI 1: ssilu; 2: (skip+ssilu)*inv2; 3: C[swp[r]]=(C[swp[r]]+ssilu)*inv2
// ---------------------------------------------------------------------------
template <typename TA, int FC, int EPI>
__global__ __launch_bounds__(256) void mgemm2(
    const TA* __restrict__ A, const bf16t* __restrict__ BT,
    bf16t* __restrict__ C, const bf16t* __restrict__ skip,
    int M, int N, int K, const int* __restrict__ swp)
{
    const int tid = threadIdx.x, wave = tid >> 6, lane = tid & 63;
    const int rowBase = blockIdx.y * 128, colBase = blockIdx.x * (FC * 16);
    const int kd = (lane >> 4) << 3;
    const int r0 = rowBase + wave * 32 + (lane & 15);
    const int r0c = r0 < M ? r0 : (M - 1);
    const int r1c = (r0 + 16) < M ? (r0 + 16) : (M - 1);
    const int colF = colBase + (lane & 15);

    f32x4 zv = {0.f, 0.f, 0.f, 0.f};
    f32x4 acc[2][FC];
#pragma unroll
    for (int p = 0; p < 2; p++)
#pragma unroll
        for (int q = 0; q < FC; q++) acc[p][q] = zv;

    for (int k0 = 0; k0 < K; k0 += 32) {
        u16x8 a0, a1;
        if constexpr (sizeof(TA) == 2) {
            a0 = *(const u16x8*)((const bf16t*)A + (size_t)r0c * K + k0 + kd);
            a1 = *(const u16x8*)((const bf16t*)A + (size_t)r1c * K + k0 + kd);
        } else {
            const float4* s0 = (const float4*)((const float*)A + (size_t)r0c * K + k0 + kd);
            const float4* s1 = (const float4*)((const float*)A + (size_t)r1c * K + k0 + kd);
            a0 = cvt8(s0[0], s0[1]);
            a1 = cvt8(s1[0], s1[1]);
        }
#pragma unroll
        for (int fc = 0; fc < FC; fc++) {
            u16x8 b = *(const u16x8*)(BT + (size_t)(colF + fc * 16) * K + k0 + kd);
            acc[0][fc] = __builtin_amdgcn_mfma_f32_16x16x32_bf16(
                *(s16x8*)&a0, *(s16x8*)&b, acc[0][fc], 0, 0, 0);
            acc[1][fc] = __builtin_amdgcn_mfma_f32_16x16x32_bf16(
                *(s16x8*)&a1, *(s16x8*)&b, acc[1][fc], 0, 0, 0);
        }
    }

    const int rB = rowBase + wave * 32 + ((lane >> 4) << 2);
#pragma unroll
    for (int fr = 0; fr < 2; fr++) {
#pragma unroll
        for (int r = 0; r < 4; r++) {
            int row = rB + fr * 16 + r;
            if (row >= M) continue;
#pragma unroll
            for (int fc = 0; fc < FC; fc++) {
                int col = colF + fc * 16;
                float v = acc[fr][fc][r];
                if (EPI == 1) {
                    C[(size_t)row * N + col] = f2bf(ssilu(v));
                } else if (EPI == 2) {
                    float sk = bf2f(skip[(size_t)row * N + col]);
                    C[(size_t)row * N + col] = f2bf((sk + ssilu(v)) * INV_SQRT2f);
                } else {
                    int tr = swp[row];
                    bf16t* cp = &C[(size_t)tr * N + col];
                    *cp = f2bf((bf2f(*cp) + ssilu(v)) * INV_SQRT2f);
                }
            }
        }
    }
}

// ---------------------------------------------------------------------------
// MFMA GEMM with concat-gather A (for edge embedding): A row r =
// concat(hA[gS[r]], hA[gT[r]], X[r,0:w2]). B from pre-transposed BT (KP rows).
// ---------------------------------------------------------------------------
__global__ __launch_bounds__(256) void mgemmA1(
    const bf16t* __restrict__ BT,
    bf16t* __restrict__ C,
    int M, int N, int K, int KP,
    const float* __restrict__ hA, const int* __restrict__ gS,
    const int* __restrict__ gT, const bf16t* __restrict__ X, int w2)
{
    __shared__ __align__(16) ushort As[128][40];
    __shared__ __align__(16) ushort Bs[64][40];
    const int tid = threadIdx.x;
    const int wave = tid >> 6, lane = tid & 63;
    const int rowBase = blockIdx.y * 128, colBase = blockIdx.x * 64;

    const int ar = tid >> 1;
    const int ah = (tid & 1) << 4;
    const int arow = rowBase + ar;
    const int arowC = arow < M ? arow : (M - 1);
    const int ia = gS[arowC], ibx = gT[arowC];

    const int bcol = tid & 63;
    const int bk0 = (tid >> 6) << 3;

    f32x4 zv = {0.f, 0.f, 0.f, 0.f};
    f32x4 acc[2][4];
#pragma unroll
    for (int p = 0; p < 2; p++)
#pragma unroll
        for (int q = 0; q < 4; q++) acc[p][q] = zv;

    const ushort* asBase = &As[0][0];
    const ushort* bsBase = &Bs[0][0];
    const int aoff = (wave * 32 + (lane & 15)) * 40 + ((lane >> 4) << 3);
    const int boff = (lane & 15) * 40 + ((lane >> 4) << 3);

    for (int k0 = 0; k0 < K; k0 += 32) {
        u16x8 a0{}, a1{};
        const int kk = k0 + ah;
        if (kk < 128) {
            const float4* s = (const float4*)(hA + (size_t)ia * 128 + kk);
            a0 = cvt8(s[0], s[1]); a1 = cvt8(s[2], s[3]);
        } else if (kk < 256) {
            const float4* s = (const float4*)(hA + (size_t)ibx * 128 + (kk - 128));
            a0 = cvt8(s[0], s[1]); a1 = cvt8(s[2], s[3]);
        } else if (kk < K && kk - 256 < w2) {
            const u16x8* s = (const u16x8*)(X + (size_t)arowC * w2 + (kk - 256));
            a0 = s[0]; a1 = s[1];
        }
        u16x8 bv = *(const u16x8*)(BT + (size_t)(colBase + bcol) * KP + k0 + bk0);
        __syncthreads();
        *(u16x8*)&As[ar][ah] = a0;
        *(u16x8*)&As[ar][ah + 8] = a1;
        *(u16x8*)&Bs[bcol][bk0] = bv;
        __syncthreads();

        u16x8 af0 = *(const u16x8*)(asBase + aoff);
        u16x8 af1 = *(const u16x8*)(asBase + aoff + 16 * 40);
#pragma unroll
        for (int fc = 0; fc < 4; fc++) {
            u16x8 bf = *(const u16x8*)(bsBase + boff + fc * 16 * 40);
            acc[0][fc] = __builtin_amdgcn_mfma_f32_16x16x32_bf16(
                *(s16x8*)&af0, *(s16x8*)&bf, acc[0][fc], 0, 0, 0);
            acc[1][fc] = __builtin_amdgcn_mfma_f32_16x16x32_bf16(
                *(s16x8*)&af1, *(s16x8*)&bf, acc[1][fc], 0, 0, 0);
        }
    }

    const int rBase = rowBase + wave * 32 + ((lane >> 4) << 2);
    const int cBase = colBase + (lane & 15);
#pragma unroll
    for (int fr = 0; fr < 2; fr++) {
#pragma unroll
        for (int r = 0; r < 4; r++) {
            int row = rBase + fr * 16 + r;
            if (row >= M) continue;
#pragma unroll
            for (int fc = 0; fc < 4; fc++) {
                int col = cBase + fc * 16;
                C[(size_t)row * N + col] = f2bf(ssilu(acc[fr][fc][r]));
            }
        }
    }
}

// ---------------------------------------------------------------------------
// MFMA bilinear v2: seg[id3_ca[t]] += sum_i cbf[t,i] * (xt[id3_ba[t]] @ W_i)
// WT[i][o][c] bf16 pre-transposed. A hoisted to regs; no barriers in i-loop.
// ---------------------------------------------------------------------------
__global__ __launch_bounds__(256) void k_bilinear_m(
    const bf16t* __restrict__ xtrip, const bf16t* __restrict__ cbf,
    const bf16t* __restrict__ WT,
    const int* __restrict__ id3_ba, const int* __restrict__ id3_ca,
    float* __restrict__ seg)
{
    __shared__ __align__(16) ushort xs[64][72];
    __shared__ ushort cbs[64][16];
    __shared__ int cas[64];
    const int tid = threadIdx.x, wave = tid >> 6, lane = tid & 63;
    const int t0 = blockIdx.x * 64;
    {
        int r = tid >> 2, q = (tid & 3) << 4;
        int ba = id3_ba[t0 + r];
        const u16x8* src = (const u16x8*)(xtrip + (size_t)ba * 64 + q);
        *(u16x8*)&xs[r][q] = src[0];
        *(u16x8*)&xs[r][q + 8] = src[1];
    }
    if (tid < 64) cas[tid] = id3_ca[t0 + tid];
    {
        int e = tid << 2; int r = e >> 4, c = e & 15;
        *(ushort4*)&cbs[r][c] = *(const ushort4*)(cbf + (size_t)(t0 + r) * 16 + c);
    }
    __syncthreads();
    const int kd = (lane >> 4) << 3;
    u16x8 a0 = *(const u16x8*)(&xs[wave * 16 + (lane & 15)][kd]);
    u16x8 a1 = *(const u16x8*)(&xs[wave * 16 + (lane & 15)][32 + kd]);
    const int rowo = wave * 16 + ((lane >> 4) << 2);

    float tot[4][4];
#pragma unroll
    for (int a = 0; a < 4; a++)
#pragma unroll
        for (int b = 0; b < 4; b++) tot[a][b] = 0.f;

    for (int i = 0; i < 16; i++) {
        f32x4 zv = {0.f, 0.f, 0.f, 0.f};
        f32x4 p[4] = {zv, zv, zv, zv};
        const bf16t* w = WT + ((size_t)i * 64 + (lane & 15)) * 64 + kd;
#pragma unroll
        for (int fc = 0; fc < 4; fc++) {
            u16x8 b0 = *(const u16x8*)(w + fc * 16 * 64);
            u16x8 b1 = *(const u16x8*)(w + fc * 16 * 64 + 32);
            p[fc] = __builtin_amdgcn_mfma_f32_16x16x32_bf16(
                *(s16x8*)&a0, *(s16x8*)&b0, p[fc], 0, 0, 0);
            p[fc] = __builtin_amdgcn_mfma_f32_16x16x32_bf16(
                *(s16x8*)&a1, *(s16x8*)&b1, p[fc], 0, 0, 0);
        }
#pragma unroll
        for (int r = 0; r < 4; r++) {
            float s = bf2f(cbs[rowo + r][i]);
#pragma unroll
            for (int fc = 0; fc < 4; fc++) tot[fc][r] += s * p[fc][r];
        }
    }
#pragma unroll
    for (int r = 0; r < 4; r++) {
        int ca = cas[rowo + r];
#pragma unroll
        for (int fc = 0; fc < 4; fc++) {
            int col = fc * 16 + (lane & 15);
            atomicAdd(&seg[(size_t)ca * 64 + col], tot[fc][r]);
        }
    }
}

// ---------------------------------------------------------------------------
// f32 VALU GEMM (NATOM-sized output path)
// ---------------------------------------------------------------------------
template <int EPI>
__global__ __launch_bounds__(256) void gemm64(
    const float* __restrict__ A, const float* __restrict__ B,
    float* __restrict__ C, const float* __restrict__ skip,
    int M, int N, int K)
{
    __shared__ __align__(16) float As[16][64];
    __shared__ __align__(16) float Bs[16][64];
    const int tid = threadIdx.x;
    const int tx = tid & 15, ty = tid >> 4;
    const int rowBase = blockIdx.y * 64;
    const int colBase = blockIdx.x * 64;
    const int lr = tid >> 2;
    const int lk = (tid & 3) * 4;
    const int bk = tid >> 4;
    const int bc = (tid & 15) * 4;
    int arow = rowBase + lr;
    int arowC = arow < M ? arow : (M - 1);

    float acc[4][4];
#pragma unroll
    for (int i = 0; i < 4; i++)
#pragma unroll
        for (int j = 0; j < 4; j++) acc[i][j] = 0.f;

    for (int k0 = 0; k0 < K; k0 += 16) {
        float4 a4 = *(const float4*)(A + (size_t)arowC * K + k0 + lk);
        float4 b4 = *(const float4*)(B + (size_t)(k0 + bk) * N + colBase + bc);
        __syncthreads();
        As[lk + 0][lr] = a4.x;
        As[lk + 1][lr] = a4.y;
        As[lk + 2][lr] = a4.z;
        As[lk + 3][lr] = a4.w;
        *(float4*)(&Bs[bk][bc]) = b4;
        __syncthreads();
#pragma unroll
        for (int kk = 0; kk < 16; kk++) {
            float4 av = *(const float4*)(&As[kk][ty * 4]);
            float4 bv = *(const float4*)(&Bs[kk][tx * 4]);
            float a[4] = {av.x, av.y, av.z, av.w};
            float b[4] = {bv.x, bv.y, bv.z, bv.w};
#pragma unroll
            for (int i = 0; i < 4; i++)
#pragma unroll
                for (int j = 0; j < 4; j++)
                    acc[i][j] = fmaf(a[i], b[j], acc[i][j]);
        }
    }
    const int col0 = colBase + tx * 4;
#pragma unroll
    for (int ri = 0; ri < 4; ri++) {
        int row = rowBase + ty * 4 + ri;
        if (row >= M) break;
        float* cp = C + (size_t)row * N + col0;
#pragma unroll
        for (int ci = 0; ci < 4; ci++) {
            float v = acc[ri][ci];
            if (EPI == 1) v = ssilu(v);
            if (EPI == 2) v = (skip[(size_t)row * N + col0 + ci] + ssilu(v)) * INV_SQRT2f;
            cp[ci] = v;
        }
    }
}

// ---------------------------------------------------------------------------
// per-edge multiply by (rbf[e,16] @ Wc[16,256]); SCATTER: atomicAdd f32 to idxT
// ---------------------------------------------------------------------------
template <int SCATTER, typename T>
__global__ __launch_bounds__(256) void k_mulproj(
    const T* __restrict__ in, const T* __restrict__ rvec,
    const float* __restrict__ Wp, const int* __restrict__ idxT,
    T* __restrict__ out, float* __restrict__ outf)
{
    int e = blockIdx.x;
    int j = threadIdx.x;
    __shared__ float r16[16];
    if (j < 16) r16[j] = VT<T>::load(rvec + (size_t)e * 16 + j);
    __syncthreads();
    float p = 0.f;
#pragma unroll
    for (int k = 0; k < 16; k++) p = fmaf(r16[k], Wp[k * 256 + j], p);
    float v = VT<T>::load(in + (size_t)e * 256 + j) * p;
    if (SCATTER) atomicAdd(&outf[(size_t)idxT[e] * 256 + j], v);
    else VT<T>::store(out + (size_t)e * 256 + j, v);
}

// ---------------------------------------------------------------------------
// LN(m row) * (rbf[e,16] @ Wc[16,256]) scattered into segN (f32) by idx_t
// ---------------------------------------------------------------------------
template <typename T>
__global__ __launch_bounds__(256) void k_ln_proj_scatter(
    const T* __restrict__ m, const float* __restrict__ lnw,
    const float* __restrict__ lnb, const T* __restrict__ rvec,
    const float* __restrict__ Wp, const int* __restrict__ idxT,
    float* __restrict__ segN)
{
    int e = blockIdx.x;
    int j = threadIdx.x;
    __shared__ float red[8];
    __shared__ float r16[16];
    if (j < 16) r16[j] = VT<T>::load(rvec + (size_t)e * 16 + j);
    float v = VT<T>::load(m + (size_t)e * 256 + j);
    float s = v, s2 = v * v;
#pragma unroll
    for (int off = 32; off > 0; off >>= 1) {
        s += __shfl_xor(s, off);
        s2 += __shfl_xor(s2, off);
    }
    int wid = j >> 6, lane = j & 63;
    if (lane == 0) { red[wid] = s; red[4 + wid] = s2; }
    __syncthreads();
    float tot = red[0] + red[1] + red[2] + red[3];
    float tot2 = red[4] + red[5] + red[6] + red[7];
    float mu = tot * (1.f / 256.f);
    float var = tot2 * (1.f / 256.f) - mu * mu;
    float ln = (v - mu) * rsqrtf(var + 1e-5f) * lnw[j] + lnb[j];
    float p = 0.f;
#pragma unroll
    for (int k = 0; k < 16; k++) p = fmaf(r16[k], Wp[k * 256 + j], p);
    atomicAdd(&segN[(size_t)idxT[e] * 256 + j], ln * p);
}

// ---------------------------------------------------------------------------
__global__ __launch_bounds__(128) void k_ln_acc(
    const float* __restrict__ x, const float* __restrict__ w,
    const float* __restrict__ b, float* __restrict__ out)
{
    int n = blockIdx.x;
    int j = threadIdx.x;
    __shared__ float red[4];
    float v = x[(size_t)n * 128 + j];
    float s = v, s2 = v * v;
#pragma unroll
    for (int off = 32; off > 0; off >>= 1) {
        s += __shfl_xor(s, off);
        s2 += __shfl_xor(s2, off);
    }
    int wid = j >> 6, lane = j & 63;
    if (lane == 0) { red[wid] = s; red[2 + wid] = s2; }
    __syncthreads();
    float tot = red[0] + red[1];
    float tot2 = red[2] + red[3];
    float mu = tot * (1.f / 128.f);
    float var = tot2 * (1.f / 128.f) - mu * mu;
    out[(size_t)n * 128 + j] += (v - mu) * rsqrtf(var + 1e-5f) * w[j] + b[j];
}

// ---------------------------------------------------------------------------
template <typename T>
__global__ __launch_bounds__(256) void k_addscale(
    const T* __restrict__ a, const T* __restrict__ b, T* __restrict__ y, int n4)
{
    int i = blockIdx.x * 256 + threadIdx.x;
    if (i < n4) {
        float4 av = VT<T>::load4(a + (size_t)i * 4);
        float4 bv = VT<T>::load4(b + (size_t)i * 4);
        VT<T>::store4(y + (size_t)i * 4,
                      make_float4((av.x + bv.x) * INV_SQRT2f, (av.y + bv.y) * INV_SQRT2f,
                                  (av.z + bv.z) * INV_SQRT2f, (av.w + bv.w) * INV_SQRT2f));
    }
}

// ---------------------------------------------------------------------------
typedef bf16t T;
static bool try_run(void* const* d_in, void* d_out, void* d_ws, size_t ws_size, hipStream_t stream)
{
    const float* D            = (const float*)d_in[0];
    const float* cosphi       = (const float*)d_in[1];
    const float* atom_emb     = (const float*)d_in[2];
    const float* W_rbf3       = (const float*)d_in[3];
    const float* W_rbf_h      = (const float*)d_in[4];
    const float* W_rbf_out    = (const float*)d_in[5];
    const float* W_cbf_down   = (const float*)d_in[6];
    const float* W_edge_emb   = (const float*)d_in[7];
    const float* ib_dense_ca  = (const float*)d_in[8];
    const float* ib_trip_dense_ba = (const float*)d_in[9];
    const float* ib_trip_mlp_rbf  = (const float*)d_in[10];
    const float* ib_trip_down     = (const float*)d_in[11];
    const float* ib_trip_bilinear = (const float*)d_in[12];
    const float* ib_trip_up_ca    = (const float*)d_in[13];
    const float* ib_trip_up_ac    = (const float*)d_in[14];
    const float* ib_res_before    = (const float*)d_in[15];
    const float* ib_res_after     = (const float*)d_in[16];
    const float* ib_atom_dense_rbf = (const float*)d_in[17];
    const float* ib_atom_dense1    = (const float*)d_in[18];
    const float* ib_atom_res       = (const float*)d_in[19];
    const float* ib_concat_dense   = (const float*)d_in[20];
    const float* ib_res_m          = (const float*)d_in[21];
    const float* ob_dense_rbf      = (const float*)d_in[22];
    const float* ob_dense1         = (const float*)d_in[23];
    const float* ob_res            = (const float*)d_in[24];
    const float* ln_m_w            = (const float*)d_in[25];
    const float* ln_m_b            = (const float*)d_in[26];
    const float* ln_E_w            = (const float*)d_in[27];
    const float* ln_E_b            = (const float*)d_in[28];
    const int* Z       = (const int*)d_in[29];
    const int* idx_s   = (const int*)d_in[30];
    const int* idx_t   = (const int*)d_in[31];
    const int* id3_ba  = (const int*)d_in[32];
    const int* id3_ca  = (const int*)d_in[33];
    const int* id_swap = (const int*)d_in[34];

    char* base = (char*)d_ws;
    size_t off = 0;
    auto alloc = [&](size_t bytes) -> char* {
        off = (off + 255) & ~(size_t)255;
        char* p = base + off;
        off += bytes;
        return p;
    };
    T* m      = (T*)alloc((size_t)EG * 256 * 2);
    T* B1     = (T*)alloc((size_t)EG * 256 * 2);
    T* B2     = (T*)alloc((size_t)EG * 256 * 2);
    float* rbfW1 = (float*)B1;                    // alias: dead before B1 first written
    T* rbf    = (T*)alloc((size_t)EG * 16 * 2);   // persistent basis
    T* cbf    = (T*)alloc((size_t)TT * 16 * 2);
    float* h  = (float*)alloc((size_t)NATOM * 128 * 4);
    T* xtrip  = (T*)alloc((size_t)EG * 64 * 2);
    // union: seg64 (bilinear window) overlaps segN/At1/At2 (atom/out window)
    char* ub  = alloc((size_t)EG * 64 * 4);
    float* seg64 = (float*)ub;
    float* segN  = (float*)ub;
    float* At1   = (float*)(ub + (size_t)NATOM * 256 * 4);
    float* At2   = (float*)(ub + (size_t)NATOM * 256 * 4 + (size_t)NATOM * 128 * 4);
    float* wc_mlp  = (float*)alloc(16 * 256 * 4);
    float* wc_atom = (float*)alloc(16 * 256 * 4);
    float* wc_ob   = (float*)alloc(16 * 256 * 4);
    T* wt   = (T*)alloc((size_t)288 * 256 * 2);   // transposed weight scratch
    T* wtb  = (T*)alloc((size_t)16 * 64 * 64 * 2);
    if (off > ws_size) return false;
    float* out = (float*)d_out;

    auto cw = [&](const float* W, int K, int N) {
        int KP = (K + 31) & ~31;
        k_wt<<<(N * KP + 255) / 256, 256, 0, stream>>>(W, wt, K, KP, N);
        return KP;
    };
    // bf16-A MFMA GEMM, N=256 (FC=8)
    auto m256 = [&](int epi, const T* A, const float* W, T* C, const T* skip, int Kk) {
        cw(W, Kk, 256);
        dim3 grid(2, (EG + 127) / 128);
        if (epi == 1)
            mgemm2<T, 8, 1><<<grid, 256, 0, stream>>>(A, wt, C, skip, EG, 256, Kk, nullptr);
        else
            mgemm2<T, 8, 2><<<grid, 256, 0, stream>>>(A, wt, C, skip, EG, 256, Kk, nullptr);
    };
    auto out_block = [&](int i) {
        k_wcomb<<<1, 256, 0, stream>>>(W_rbf_out, ob_dense_rbf + (size_t)i * 16 * 256, wc_ob);
        hipMemsetAsync(segN, 0, (size_t)NATOM * 256 * 4, stream);
        k_ln_proj_scatter<T><<<EG, 256, 0, stream>>>(m, ln_m_w + (size_t)i * 256, ln_m_b + (size_t)i * 256,
                                                     rbf, wc_ob, idx_t, segN);
        {
            dim3 g(2, (NATOM + 63) / 64);
            gemm64<1><<<g, 256, 0, stream>>>(segN, ob_dense1 + (size_t)i * 256 * 128, At1, nullptr, NATOM, 128, 256);
        }
        for (int r = 0; r < 2; r++) {
            const float* W0 = ob_res + ((size_t)i * 2 + r) * 2 * 128 * 128;
            const float* W1 = W0 + 128 * 128;
            dim3 g(2, (NATOM + 63) / 64);
            gemm64<1><<<g, 256, 0, stream>>>(At1, W0, At2, nullptr, NATOM, 128, 128);
            gemm64<2><<<g, 256, 0, stream>>>(At2, W1, At1, At1, NATOM, 128, 128);
        }
        k_ln_acc<<<NATOM, 128, 0, stream>>>(At1, ln_E_w + (size_t)i * 128, ln_E_b + (size_t)i * 128, out);
    };

    hipMemsetAsync(out, 0, (size_t)NATOM * 128 * 4, stream);
    k_rbf<T><<<(EG + 255) / 256, 256, 0, stream>>>(D, W_cbf_down, rbf, rbfW1);
    k_cbf<T><<<(TT + 255) / 256, 256, 0, stream>>>(cosphi, id3_ca, rbfW1, cbf);
    k_hgather<<<(NATOM * 128 + 255) / 256, 256, 0, stream>>>(atom_emb, Z, h);
    {
        int KP = cw(W_edge_emb, 272, 256);
        dim3 grid(4, (EG + 127) / 128);
        mgemmA1<<<grid, 256, 0, stream>>>(wt, m, EG, 256, 272, KP, h, idx_s, idx_t, rbf, 16);
    }

    out_block(0);

    for (int i = 0; i < 2; i++) {
        // ---- triplet interaction ----
        m256(1, m, ib_dense_ca + (size_t)i * 256 * 256, B1, nullptr, 256);      // x_ca_skip
        m256(1, m, ib_trip_dense_ba + (size_t)i * 256 * 256, B2, nullptr, 256); // x_ba
        k_wcomb<<<1, 256, 0, stream>>>(W_rbf3, ib_trip_mlp_rbf + (size_t)i * 16 * 256, wc_mlp);
        k_mulproj<0, T><<<EG, 256, 0, stream>>>(B2, rbf, wc_mlp, nullptr, B2, nullptr);
        {
            cw(ib_trip_down + (size_t)i * 256 * 64, 256, 64);
            dim3 grid(1, (EG + 127) / 128);
            mgemm2<T, 4, 1><<<grid, 256, 0, stream>>>(B2, wt, xtrip, nullptr, EG, 64, 256, nullptr);
        }
        hipMemsetAsync(seg64, 0, (size_t)EG * 64 * 4, stream);
        k_wtb<<<(16 * 64 * 64 + 255) / 256, 256, 0, stream>>>(ib_trip_bilinear + (size_t)i * 64 * 16 * 64, wtb);
        k_bilinear_m<<<TT / 64, 256, 0, stream>>>(xtrip, cbf, wtb, id3_ba, id3_ca, seg64);
        {
            cw(ib_trip_up_ca + (size_t)i * 64 * 256, 64, 256);
            dim3 grid(2, (EG + 127) / 128);
            mgemm2<float, 8, 1><<<grid, 256, 0, stream>>>(seg64, wt, B2, nullptr, EG, 256, 64, nullptr);
            cw(ib_trip_up_ac + (size_t)i * 64 * 256, 64, 256);
            mgemm2<float, 8, 3><<<grid, 256, 0, stream>>>(seg64, wt, B2, nullptr, EG, 256, 64, id_swap);
        }
        k_addscale<T><<<(EG * 256 / 4 + 255) / 256, 256, 0, stream>>>(B1, B2, B1, EG * 256 / 4);
        // ---- edge update ----
        {
            const float* W0 = ib_res_before + (size_t)i * 2 * 256 * 256;
            const float* W1 = W0 + 256 * 256;
            m256(1, B1, W0, B2, nullptr, 256);
            m256(2, B2, W1, B1, B1, 256);
        }
        k_addscale<T><<<(EG * 256 / 4 + 255) / 256, 256, 0, stream>>>(B1, m, B1, EG * 256 / 4);
        {
            const float* W0 = ib_res_after + (size_t)i * 2 * 256 * 256;
            const float* W1 = W0 + 256 * 256;
            m256(1, B1, W0, B2, nullptr, 256);
            m256(2, B2, W1, B1, B1, 256);
        }
        // ---- atom update ----
        k_wcomb<<<1, 256, 0, stream>>>(W_rbf_h, ib_atom_dense_rbf + (size_t)i * 16 * 256, wc_atom);
        hipMemsetAsync(segN, 0, (size_t)NATOM * 256 * 4, stream);
        k_mulproj<1, T><<<EG, 256, 0, stream>>>(B1, rbf, wc_atom, idx_t, nullptr, segN);
        {
            dim3 g(2, (NATOM + 63) / 64);
            gemm64<1><<<g, 256, 0, stream>>>(segN, ib_atom_dense1 + (size_t)i * 256 * 128, At1, nullptr, NATOM, 128, 256);
            for (int r = 0; r < 2; r++) {
                const float* W0 = ib_atom_res + ((size_t)i * 2 + r) * 2 * 128 * 128;
                const float* W1 = W0 + 128 * 128;
                gemm64<1><<<g, 256, 0, stream>>>(At1, W0, At2, nullptr, NATOM, 128, 128);
                gemm64<2><<<g, 256, 0, stream>>>(At2, W1, At1, At1, NATOM, 128, 128);
            }
        }
        k_addscale<float><<<(NATOM * 128 / 4 + 255) / 256, 256, 0, stream>>>(h, At1, h, NATOM * 128 / 4);
        // ---- edge embedding refresh ----
        {
            int KP = cw(ib_concat_dense + (size_t)i * 512 * 256, 512, 256);
            dim3 grid(4, (EG + 127) / 128);
            mgemmA1<<<grid, 256, 0, stream>>>(wt, B2, EG, 256, 512, KP, h, idx_s, idx_t, B1, 256);
        }
        {
            const float* W0 = ib_res_m + (size_t)i * 2 * 256 * 256;
            const float* W1 = W0 + 256 * 256;
            m256(1, B2, W0, B1, nullptr, 256);
            m256(2, B1, W1, B2, B2, 256);
        }
        k_addscale<T><<<(EG * 256 / 4 + 255) / 256, 256, 0, stream>>>(m, B2, m, EG * 256 / 4);

        out_block(i + 1);
    }
    return true;
}

extern "C" void kernel_launch(void* const* d_in, const int* in_sizes, int n_in,
                              void* d_out, int out_size, void* d_ws, size_t ws_size,
                              hipStream_t stream)
{
    if (try_run(d_in, d_out, d_ws, ws_size, stream)) return;
    float v = 3000.0f + (float)(ws_size >> 20);
    k_fill<<<(NATOM * 128 + 255) / 256, 256, 0, stream>>>((float*)d_out, NATOM * 128, v);
}